// Round 15
// baseline (765.185 us; speedup 1.0000x reference)
//
#include <hip/hip_runtime.h>
#include <stdint.h>

#define DEVI static __device__ __forceinline__
typedef unsigned short u16;
typedef __bf16 bhalf8 __attribute__((ext_vector_type(8)));
typedef float f32x4 __attribute__((ext_vector_type(4)));

DEVI u16 f2bf(float f) {
  union { float f; unsigned u; } v; v.f = f;
  unsigned r = v.u + 0x7FFFu + ((v.u >> 16) & 1u);
  return (u16)(r >> 16);
}
DEVI float bf2f(u16 h) {
  union { unsigned u; float f; } v; v.u = ((unsigned)h) << 16;
  return v.f;
}
DEVI f32x4 MFMA(bhalf8 a, bhalf8 b, f32x4 c) {
  return __builtin_amdgcn_mfma_f32_16x16x32_bf16(a, b, c, 0, 0, 0);
}
DEVI bhalf8 LD8(const u16* p) { return *(const bhalf8*)p; }
DEVI f32x4 zero4() { f32x4 z = {0.f, 0.f, 0.f, 0.f}; return z; }

// async global->LDS, 16B per lane, dest = wave-uniform base + lane*16
#define GLDS16(gp, lp) __builtin_amdgcn_global_load_lds( \
    (const __attribute__((address_space(1))) void*)(gp), \
    (__attribute__((address_space(3))) void*)(lp), 16, 0, 0)

// ================= prep / elementwise =================

__global__ __launch_bounds__(256) void nsa_hnorm(const float* __restrict__ x, const float* __restrict__ pos,
    const float* __restrict__ pew, const float* __restrict__ peb,
    const float* __restrict__ gamma, u16* __restrict__ hhi, u16* __restrict__ hlo) {
  int n = blockIdx.x, t = threadIdx.x;
  int blk = n >> 6;
  __shared__ float spm[3];
  if (t < 64) {
    const float* p = pos + (size_t)(blk * 64 + t) * 3;
    float a = p[0], b = p[1], c = p[2];
#pragma unroll
    for (int o = 32; o; o >>= 1) { a += __shfl_down(a, o); b += __shfl_down(b, o); c += __shfl_down(c, o); }
    if (t == 0) { spm[0] = a * (1.f/64.f); spm[1] = b * (1.f/64.f); spm[2] = c * (1.f/64.f); }
  }
  __syncthreads();
  float r0 = pos[(size_t)n*3+0] - spm[0];
  float r1 = pos[(size_t)n*3+1] - spm[1];
  float r2 = pos[(size_t)n*3+2] - spm[2];
  int c0 = t, c1 = t + 256;
  const float* xr = x + (size_t)n * 512;
  float v0 = xr[c0] + r0*pew[c0] + r1*pew[512+c0] + r2*pew[1024+c0] + peb[c0];
  float v1 = xr[c1] + r0*pew[c1] + r1*pew[512+c1] + r2*pew[1024+c1] + peb[c1];
  float ss = v0*v0 + v1*v1;
#pragma unroll
  for (int o = 32; o; o >>= 1) ss += __shfl_down(ss, o);
  __shared__ float red[4];
  if ((t & 63) == 0) red[t >> 6] = ss;
  __syncthreads();
  float rms = 1.0f / sqrtf((red[0]+red[1]+red[2]+red[3]) * (1.0f/512.0f) + 1e-6f);
  float h0 = v0 * rms * gamma[c0], h1 = v1 * rms * gamma[c1];
  u16 a0 = f2bf(h0); hhi[(size_t)n*512+c0] = a0; hlo[(size_t)n*512+c0] = f2bf(h0 - bf2f(a0));
  u16 a1 = f2bf(h1); hhi[(size_t)n*512+c1] = a1; hlo[(size_t)n*512+c1] = f2bf(h1 - bf2f(a1));
}

// merged prep: [0,1792) WcatT; [1792,2304) rope tables; [2304,2368) w_out^T;
// [2368,2432) k_w2^T (split); [2432,2496) v_w2^T. All input-only -> zero dependencies.
__global__ __launch_bounds__(256) void nsa_wcat_rope(const float* __restrict__ wq, const float* __restrict__ wk,
    const float* __restrict__ wv, const float* __restrict__ wc, u16* __restrict__ hi, u16* __restrict__ lo,
    float* __restrict__ ct, float* __restrict__ st,
    const float* __restrict__ wo, u16* __restrict__ woh,
    const float* __restrict__ kw2, u16* __restrict__ w2h, u16* __restrict__ w2l,
    const float* __restrict__ vw2, u16* __restrict__ w2vh) {
  int bidx = blockIdx.x;
  if (bidx < 1792) {
    int idx = bidx * 256 + threadIdx.x;  // 896*512
    int k = idx & 511, n = idx >> 9;
    float v;
    if (n < 512) v = wq[(size_t)k*512 + n];
    else if (n < 640) v = wk[(size_t)k*128 + n - 512];
    else if (n < 768) v = wv[(size_t)k*128 + n - 640];
    else if (n < 792) v = wc[(size_t)k*24 + n - 768];
    else v = 0.f;
    u16 h = f2bf(v); hi[idx] = h; lo[idx] = f2bf(v - bf2f(h));
  } else if (bidx < 2304) {
    int idx = (bidx - 1792) * 256 + threadIdx.x;  // 4096*32
    int s = idx >> 5, i = idx & 31;
    float e = (float)(2*i) * (1.0f/64.0f);
    float inv = 1.0f / powf(10000.0f, e);
    float f = (float)s * inv;
    ct[idx] = cosf(f); st[idx] = sinf(f);
  } else {
    __shared__ float tile[64][65];
    const float* src; u16* dhi; u16* dlo = nullptr; int K, N, k0, n0;
    if (bidx < 2368) {
      int j = bidx - 2304; src = wo; dhi = woh; K = 512; N = 512;
      k0 = (j & 7) * 64; n0 = (j >> 3) * 64;
    } else if (bidx < 2432) {
      int j = bidx - 2368; src = kw2; dhi = w2h; dlo = w2l; K = 4096; N = 64;
      k0 = j * 64; n0 = 0;
    } else {
      int j = bidx - 2432; src = vw2; dhi = w2vh; K = 4096; N = 64;
      k0 = j * 64; n0 = 0;
    }
    int t = threadIdx.x, r = t >> 2, c0 = (t & 3) * 16;
#pragma unroll
    for (int j = 0; j < 16; ++j) tile[r][c0+j] = src[(size_t)(k0+r)*N + n0 + c0 + j];
    __syncthreads();
    size_t ob = (size_t)(n0 + r)*K + k0 + c0;
#pragma unroll
    for (int j = 0; j < 16; ++j) {
      float v = tile[c0+j][r];
      u16 h = f2bf(v); dhi[ob+j] = h;
      if (dlo) dlo[ob+j] = f2bf(v - bf2f(h));
    }
  }
}

// merged post-projection transposes: [0,1024) v16 -> vT; [1024,9216) w1 transposes
// (z=0: k_w1 -> w1kh/w1kl split; z=1: v_w1 -> w1vh). Both independent, run after projection.
__global__ __launch_bounds__(256) void nsa_vT_wT(const u16* __restrict__ v16, u16* __restrict__ vT,
    const float* __restrict__ kw1, u16* __restrict__ w1kh, u16* __restrict__ w1kl,
    const float* __restrict__ vw1, u16* __restrict__ w1vh) {
  if (blockIdx.x < 1024) {
    int blk = blockIdx.x;  // (b*2+kh)*64 + chunk
    int st = (blk & 63) * 64, bkh = blk >> 6;
    __shared__ u16 tile[64][72];
    int t = threadIdx.x;
    int s = t >> 2, c0 = (t & 3) * 16;
    const u16* src = v16 + ((size_t)bkh*4096 + st + s) * 64;
    *(int4*)&tile[s][c0]   = *(const int4*)&src[c0];
    *(int4*)&tile[s][c0+8] = *(const int4*)&src[c0+8];
    __syncthreads();
    int d = t >> 2, s0 = (t & 3) * 16;
    u16* dst = vT + ((size_t)bkh*64 + d)*4096 + st + s0;
#pragma unroll
    for (int j = 0; j < 16; ++j) dst[j] = tile[s0+j][d];
  } else {
    int j = blockIdx.x - 1024;          // [0, 8192)
    int z = j >> 12, rem = j & 4095;    // 4096 blocks per matrix (64x64 tiles of 4096x4096)
    int k0 = (rem >> 6) * 64, n0 = (rem & 63) * 64;
    const float* src = z ? vw1 : kw1;
    u16* dhi = z ? w1vh : w1kh;
    u16* dlo = z ? nullptr : w1kl;
    __shared__ float tile[64][65];
    constexpr int K = 4096, N = 4096;
    int t = threadIdx.x, r = t >> 2, c0 = (t & 3) * 16;
#pragma unroll
    for (int jj = 0; jj < 16; ++jj) tile[r][c0+jj] = src[(size_t)(k0+r)*N + n0 + c0 + jj];
    __syncthreads();
    size_t ob = (size_t)(n0 + r)*K + k0 + c0;
#pragma unroll
    for (int jj = 0; jj < 16; ++jj) {
      float v = tile[c0+jj][r];
      u16 h = f2bf(v); dhi[ob+jj] = h;
      if (dlo) dlo[ob+jj] = f2bf(v - bf2f(h));
    }
  }
}

// merged reduce of stage-2 partials: idx<81920 -> ck hi/lo (B,KH,80,64); else cvT (B,KH,64,96)
__global__ __launch_bounds__(256) void nsa_red_ckcv(const float* __restrict__ part,
    const float* __restrict__ mem_k, const float* __restrict__ kb2,
    const float* __restrict__ mem_v, const float* __restrict__ vb2,
    u16* __restrict__ ckh, u16* __restrict__ ckl, u16* __restrict__ cvT) {
  int idx = blockIdx.x * 256 + threadIdx.x;
  if (idx < 81920) {
    int d = idx & 63, n = (idx >> 6) % 80, bkh = idx / (80*64);
    int kh = bkh & 1;
    float v;
    if (n == 0) v = mem_k[kh*64 + d];
    else if (n <= 64) {
      v = kb2[d];
      int m = bkh*64 + (n - 1);
#pragma unroll
      for (int kc = 0; kc < 16; ++kc) v += part[((size_t)kc*1024 + m)*64 + d];
    } else v = 0.f;
    u16 h = f2bf(v); ckh[idx] = h; ckl[idx] = f2bf(v - bf2f(h));
  } else if (idx < 81920 + 98304) {
    int j = idx - 81920;
    int cc = j % 96, d = (j / 96) & 63, bkh = j / (96*64);
    int kh = bkh & 1;
    const float* pv = part + (size_t)16*1024*64;
    float v;
    if (cc == 0) v = mem_v[kh*64 + d];
    else if (cc <= 64) {
      v = vb2[d];
      int m = bkh*64 + (cc - 1);
#pragma unroll
      for (int kc = 0; kc < 16; ++kc) v += pv[((size_t)kc*1024 + m)*64 + d];
    } else v = 0.f;
    cvT[j] = f2bf(v);
  }
}

__global__ __launch_bounds__(256) void nsa_sentinel(float* __restrict__ o, int n, float val) {
  int i = blockIdx.x * 256 + threadIdx.x;
  if (i < n) o[i] = val;
}

// ================= GEMMs =================
// C = A @ B^T. 2-phase dbuf LDS, global_load_lds w16, both-sides XOR swizzle.
// EPI 0 (projection, single launch grid(256,7)): runtime dsp = (n0 <= 512); A-reuse swizzle.
// EPI 2: plain f32 out (p_sin = out), generic XCD swizzle.
template<bool SPLIT, int EPI>
__global__ __launch_bounds__(256) void nsa_gemm(const u16* __restrict__ Ah, const u16* __restrict__ Al,
    const u16* __restrict__ Bh, const u16* __restrict__ Bl, int K, int N,
    const float* __restrict__ p_cos, float* __restrict__ p_sin,
    u16* __restrict__ out_hi, u16* __restrict__ out_lo, float* __restrict__ og,
    const float* __restrict__ kpos, const float* __restrict__ vpos,
    u16* __restrict__ krb, u16* __restrict__ kbh, u16* __restrict__ kbl,
    u16* __restrict__ v16o, u16* __restrict__ vbh) {
  constexpr int NB = SPLIT ? 4 : 2;
  __shared__ u16 sm[NB * 2 * 4096];
  const int t = threadIdx.x, w = t >> 6, l = t & 63;
  const int wm = w >> 1, wn = w & 1;
  int m0, n0;
  if constexpr (EPI == 0) {
    const int nper = (int)gridDim.y;
    const int bid = blockIdx.y * 256 + blockIdx.x;
    const int xcd = bid & 7, j = bid >> 3;
    const int mg = j / (8*nper), rem = j % (8*nper);
    const int nn = rem >> 3, mi = rem & 7;
    m0 = ((xcd * 4 + mg) * 8 + mi) * 128;
    n0 = nn * 128;
  } else {
    const int MBn = gridDim.x;
    const int nwg = MBn * gridDim.y;
    const int bid = blockIdx.y * MBn + blockIdx.x;
    const int swz = (bid & 7) * (nwg >> 3) + (bid >> 3);
    m0 = (swz % MBn) * 128; n0 = (swz / MBn) * 128;
  }
  const bool dsp = SPLIT && (EPI != 0 || n0 <= 512);  // runtime precision per block
  const int row = l & 15;
  const int kc8 = ((l >> 4) ^ ((l >> 1) & 3)) * 8;
  const int gsc = ((l & 3) ^ ((l >> 3) & 3)) * 8;
  const int sr = l >> 2;
  f32x4 acc[4][4];
#pragma unroll
  for (int a = 0; a < 4; ++a)
#pragma unroll
    for (int b = 0; b < 4; ++b) acc[a][b] = zero4();

  auto STAGE = [&](int buf, int k0) {
    u16* base = sm + buf * NB * 4096;
#pragma unroll
    for (int s2 = 0; s2 < 2; ++s2) {
      int seg = w*2 + s2;
      int r = seg*16 + sr;
      size_t ga = (size_t)(m0 + r)*K + k0 + gsc;
      size_t gb = (size_t)(n0 + r)*K + k0 + gsc;
      GLDS16(&Ah[ga], base + seg*512);
      GLDS16(&Bh[gb], base + 4096 + seg*512);
      if (SPLIT && dsp) {
        GLDS16(&Al[ga], base + 2*4096 + seg*512);
        GLDS16(&Bl[gb], base + 3*4096 + seg*512);
      }
    }
  };

  const int nt = K >> 5;
  STAGE(0, 0);
  __syncthreads();
  int cur = 0;
  for (int kt = 0; kt < nt; ++kt) {
    if (kt + 1 < nt) STAGE(cur ^ 1, (kt + 1) * 32);
    u16* bA  = sm + cur * NB * 4096;
    u16* bB  = bA + 4096;
    u16* bAl = bA + 2*4096;
    u16* bBl = bA + 3*4096;
    bhalf8 af[4], afl[4];
#pragma unroll
    for (int mf = 0; mf < 4; ++mf) {
      af[mf] = LD8(&bA[(wm*64 + mf*16 + row)*32 + kc8]);
      if (dsp) afl[mf] = LD8(&bAl[(wm*64 + mf*16 + row)*32 + kc8]);
    }
#pragma unroll
    for (int nf = 0; nf < 4; ++nf) {
      bhalf8 bfh = LD8(&bB[(wn*64 + nf*16 + row)*32 + kc8]);
      bhalf8 bfl;
      if (dsp) bfl = LD8(&bBl[(wn*64 + nf*16 + row)*32 + kc8]);
#pragma unroll
      for (int mf = 0; mf < 4; ++mf) {
        acc[mf][nf] = MFMA(af[mf], bfh, acc[mf][nf]);
        if (dsp) {
          acc[mf][nf] = MFMA(af[mf], bfl, acc[mf][nf]);
          acc[mf][nf] = MFMA(afl[mf], bfh, acc[mf][nf]);
        }
      }
    }
    __syncthreads();
    cur ^= 1;
  }
  if constexpr (EPI == 0) {
    if (n0 < 512) {
      // q columns: fused GPT-NeoX rotary. cols c (dd<32) pair with c+32 = acc[mf][nf+2].
#pragma unroll
      for (int mf = 0; mf < 4; ++mf)
#pragma unroll
        for (int i = 0; i < 4; ++i) {
          int r = m0 + wm*64 + mf*16 + (l >> 4)*4 + i;
          int s = r & 4095, b = r >> 12;
#pragma unroll
          for (int nf = 0; nf < 2; ++nf) {
            int c = n0 + wn*64 + nf*16 + (l & 15);
            int hq = c >> 6, dd = c & 31;
            float t1 = acc[mf][nf][i], t2 = acc[mf][nf+2][i];
            float cs = p_cos[s*32 + dd], sn = p_sin[s*32 + dd];
            float o1 = t1*cs - t2*sn, o2 = t2*cs + t1*sn;
            size_t ob = (((size_t)(b*8 + hq))*4096 + s)*64;
            u16 h1 = f2bf(o1); out_hi[ob+dd] = h1;    out_lo[ob+dd] = f2bf(o1 - bf2f(h1));
            u16 h2 = f2bf(o2); out_hi[ob+dd+32] = h2; out_lo[ob+dd+32] = f2bf(o2 - bf2f(h2));
          }
        }
    } else if (n0 == 512) {
      // k columns: fused rotary -> krb; (k + k_pos) split -> kbh/kbl
      int kh = wn;
#pragma unroll
      for (int mf = 0; mf < 4; ++mf)
#pragma unroll
        for (int i = 0; i < 4; ++i) {
          int r = m0 + wm*64 + mf*16 + (l >> 4)*4 + i;
          int s = r & 4095, b = r >> 12;
          int n = s >> 6, sl = s & 63;
          size_t krbase = ((size_t)(b*2 + kh)*4096 + s)*64;
          size_t kbbase = ((size_t)(b*128 + kh*64 + n))*4096 + sl*64;
#pragma unroll
          for (int nf = 0; nf < 2; ++nf) {
            int dd = nf*16 + (l & 15);
            float t1 = acc[mf][nf][i], t2 = acc[mf][nf+2][i];
            float cs = p_cos[s*32 + dd], sn = p_sin[s*32 + dd];
            krb[krbase + dd]      = f2bf(t1*cs - t2*sn);
            krb[krbase + dd + 32] = f2bf(t2*cs + t1*sn);
          }
#pragma unroll
          for (int nf = 0; nf < 4; ++nf) {
            int dk = nf*16 + (l & 15);
            float v = acc[mf][nf][i] + kpos[(kh*64 + sl)*64 + dk];
            u16 h = f2bf(v);
            kbh[kbbase + dk] = h;
            kbl[kbbase + dk] = f2bf(v - bf2f(h));
          }
        }
    } else if (n0 == 640) {
      // v columns: v16 bf16 + (v + v_pos) -> vbh (plain)
      int kh = wn;
#pragma unroll
      for (int mf = 0; mf < 4; ++mf)
#pragma unroll
        for (int i = 0; i < 4; ++i) {
          int r = m0 + wm*64 + mf*16 + (l >> 4)*4 + i;
          int s = r & 4095, b = r >> 12;
          int n = s >> 6, sl = s & 63;
          size_t v16base = ((size_t)(b*2 + kh)*4096 + s)*64;
          size_t vbbase = ((size_t)(b*128 + kh*64 + n))*4096 + sl*64;
#pragma unroll
          for (int nf = 0; nf < 4; ++nf) {
            int dv = nf*16 + (l & 15);
            float vv = acc[mf][nf][i];
            v16o[v16base + dv] = f2bf(vv);
            vbh[vbbase + dv] = f2bf(vv + vpos[(kh*64 + sl)*64 + dv]);
          }
        }
    } else {
#pragma unroll
      for (int mf = 0; mf < 4; ++mf)
#pragma unroll
        for (int nf = 0; nf < 4; ++nf)
#pragma unroll
          for (int i = 0; i < 4; ++i) {
            int r = m0 + wm*64 + mf*16 + (l >> 4)*4 + i;
            int c = n0 + wn*64 + nf*16 + (l & 15);
            if (c < 792) og[(size_t)r*24 + (c - 768)] = 1.0f / (1.0f + expf(-acc[mf][nf][i]));
          }
    }
  } else {  // EPI == 2
#pragma unroll
    for (int mf = 0; mf < 4; ++mf)
#pragma unroll
      for (int nf = 0; nf < 4; ++nf)
#pragma unroll
        for (int i = 0; i < 4; ++i) {
          int r = m0 + wm*64 + mf*16 + (l >> 4)*4 + i;
          int c = n0 + wn*64 + nf*16 + (l & 15);
          p_sin[(size_t)r*N + c] = acc[mf][nf][i];
        }
  }
}

// merged MLP stage-1 (R12-measured-best): grid 512. Block u<32 -> k (split, 3 MFMA, out th/tl);
// u>=32 -> v (plain, out tv). Per-XCD: 4 k-coltiles + 4 v-coltiles, m-minor. Fused bias+relu.
__global__ __launch_bounds__(256) void nsa_mlp1(const u16* __restrict__ kbh, const u16* __restrict__ kbl,
    const u16* __restrict__ vbh, const u16* __restrict__ w1kh, const u16* __restrict__ w1kl,
    const u16* __restrict__ w1vh, const float* __restrict__ kb1, const float* __restrict__ vb1,
    u16* __restrict__ th, u16* __restrict__ tl, u16* __restrict__ tv) {
  __shared__ u16 sm[4 * 2 * 4096];  // 64KB
  const int t = threadIdx.x, w = t >> 6, l = t & 63;
  const int wm = w >> 1, wn = w & 1;
  const int bid = blockIdx.x;
  const int xcd = bid & 7, u = bid >> 3;
  const bool isK = u < 32;
  const int uu = isK ? u : u - 32;
  const int m0 = (uu & 7) * 128;
  const int n0 = (xcd * 4 + (uu >> 3)) * 128;
  const u16* Ah = isK ? kbh : vbh;
  const u16* Bh = isK ? w1kh : w1vh;
  constexpr int K = 4096;
  const int row = l & 15;
  const int kc8 = ((l >> 4) ^ ((l >> 1) & 3)) * 8;
  const int gsc = ((l & 3) ^ ((l >> 3) & 3)) * 8;
  const int sr = l >> 2;
  f32x4 acc[4][4];
#pragma unroll
  for (int a = 0; a < 4; ++a)
#pragma unroll
    for (int b = 0; b < 4; ++b) acc[a][b] = zero4();

  auto STAGE = [&](int buf, int k0) {
    u16* base = sm + buf * 4 * 4096;
#pragma unroll
    for (int s2 = 0; s2 < 2; ++s2) {
      int seg = w*2 + s2;
      int r = seg*16 + sr;
      size_t ga = (size_t)(m0 + r)*K + k0 + gsc;
      size_t gb = (size_t)(n0 + r)*K + k0 + gsc;
      GLDS16(&Ah[ga], base + seg*512);
      GLDS16(&Bh[gb], base + 4096 + seg*512);
      if (isK) {
        GLDS16(&kbl[ga], base + 2*4096 + seg*512);
        GLDS16(&w1kl[gb], base + 3*4096 + seg*512);
      }
    }
  };

  STAGE(0, 0);
  __syncthreads();
  int cur = 0;
  for (int kt = 0; kt < 128; ++kt) {
    if (kt + 1 < 128) STAGE(cur ^ 1, (kt + 1) * 32);
    u16* bA  = sm + cur * 4 * 4096;
    u16* bB  = bA + 4096;
    u16* bAl = bA + 2*4096;
    u16* bBl = bA + 3*4096;
    bhalf8 af[4], afl[4];
#pragma unroll
    for (int mf = 0; mf < 4; ++mf) {
      af[mf] = LD8(&bA[(wm*64 + mf*16 + row)*32 + kc8]);
      if (isK) afl[mf] = LD8(&bAl[(wm*64 + mf*16 + row)*32 + kc8]);
    }
#pragma unroll
    for (int nf = 0; nf < 4; ++nf) {
      bhalf8 bfh = LD8(&bB[(wn*64 + nf*16 + row)*32 + kc8]);
      bhalf8 bfl;
      if (isK) bfl = LD8(&bBl[(wn*64 + nf*16 + row)*32 + kc8]);
#pragma unroll
      for (int mf = 0; mf < 4; ++mf) {
        acc[mf][nf] = MFMA(af[mf], bfh, acc[mf][nf]);
        if (isK) {
          acc[mf][nf] = MFMA(af[mf], bfl, acc[mf][nf]);
          acc[mf][nf] = MFMA(afl[mf], bfh, acc[mf][nf]);
        }
      }
    }
    __syncthreads();
    cur ^= 1;
  }
  const float* bias = isK ? kb1 : vb1;
#pragma unroll
  for (int mf = 0; mf < 4; ++mf)
#pragma unroll
    for (int nf = 0; nf < 4; ++nf)
#pragma unroll
      for (int i = 0; i < 4; ++i) {
        int r = m0 + wm*64 + mf*16 + (l >> 4)*4 + i;
        int c = n0 + wn*64 + nf*16 + (l & 15);
        float v = fmaxf(acc[mf][nf][i] + bias[c], 0.f);
        if (isK) {
          u16 h = f2bf(v);
          th[(size_t)r*4096 + c] = h;
          tl[(size_t)r*4096 + c] = f2bf(v - bf2f(h));
        } else {
          tv[(size_t)r*4096 + c] = f2bf(v);
        }
      }
}

// merged stage-2: grid (16,32). y<16 -> k (split, A=th/tl, B=w2h/w2l); y>=16 -> v (plain).
// 16 K-slices of 256 each -> deterministic partials.
__global__ __launch_bounds__(256) void nsa_gemm64m(const u16* __restrict__ th, const u16* __restrict__ tl,
    const u16* __restrict__ tv, const u16* __restrict__ w2h, const u16* __restrict__ w2l,
    const u16* __restrict__ w2vh, float* __restrict__ part) {
  __shared__ u16 sm[4 * 2 * 2048];  // 32KB
  const int t = threadIdx.x, w = t >> 6, l = t & 63;
  const int mt = blockIdx.x;
  const bool isK = blockIdx.y < 16;
  const int kc = blockIdx.y & 15;
  const u16* Ah = isK ? th : tv;
  const u16* Bh = isK ? w2h : w2vh;
  float* po = part + (isK ? 0 : (size_t)16*1024*64);
  const int row = l & 15;
  const int kc8 = ((l >> 4) ^ ((l >> 1) & 3)) * 8;
  const int gsc = ((l & 3) ^ ((l >> 3) & 3)) * 8;
  const int sr = l >> 2;
  f32x4 acc[4];
#pragma unroll
  for (int a = 0; a < 4; ++a) acc[a] = zero4();

  auto STAGE = [&](int buf, int k0) {
    u16* base = sm + buf * 4 * 2048;
    int r = w*16 + sr;
    size_t ga = (size_t)(mt*64 + r)*4096 + k0 + gsc;
    size_t gb = (size_t)r*4096 + k0 + gsc;
    GLDS16(&Ah[ga], base + w*512);
    GLDS16(&Bh[gb], base + 2048 + w*512);
    if (isK) {
      GLDS16(&tl[ga], base + 2*2048 + w*512);
      GLDS16(&w2l[gb], base + 3*2048 + w*512);
    }
  };

  STAGE(0, kc*256);
  __syncthreads();
  int cur = 0;
  for (int kt = 0; kt < 8; ++kt) {
    if (kt + 1 < 8) STAGE(cur ^ 1, kc*256 + (kt + 1) * 32);
    u16* bA  = sm + cur * 4 * 2048;
    u16* bB  = bA + 2048;
    u16* bAl = bA + 2*2048;
    u16* bBl = bA + 3*2048;
    bhalf8 a = LD8(&bA[(w*16 + row)*32 + kc8]);
    bhalf8 al;
    if (isK) al = LD8(&bAl[(w*16 + row)*32 + kc8]);
#pragma unroll
    for (int nf = 0; nf < 4; ++nf) {
      bhalf8 b = LD8(&bB[(nf*16 + row)*32 + kc8]);
      bhalf8 bl;
      if (isK) bl = LD8(&bBl[(nf*16 + row)*32 + kc8]);
      acc[nf] = MFMA(a, b, acc[nf]);
      if (isK) {
        acc[nf] = MFMA(a, bl, acc[nf]);
        acc[nf] = MFMA(al, b, acc[nf]);
      }
    }
    __syncthreads();
    cur ^= 1;
  }
#pragma unroll
  for (int nf = 0; nf < 4; ++nf)
#pragma unroll
    for (int i = 0; i < 4; ++i) {
      int m = mt*64 + w*16 + (l >> 4)*4 + i;
      int d = nf*16 + (l & 15);
      po[((size_t)kc*1024 + m)*64 + d] = acc[nf][i];
    }
}

// ================= attention =================

// merged comp+slide: blocks [0,512) = slide (writes comb_s); [512,1536) = comp (writes comb_c + imp).
__global__ __launch_bounds__(256) void nsa_attn_cs(const u16* __restrict__ qrh, const u16* __restrict__ qrl,
    const u16* __restrict__ ckh, const u16* __restrict__ ckl, const u16* __restrict__ cvT,
    const u16* __restrict__ kr, const u16* __restrict__ vT, const float* __restrict__ g32,
    u16* __restrict__ comb_c, u16* __restrict__ comb_s, float* __restrict__ imp) {
  __shared__ u16 smem[26624];
  __shared__ float sImp[4 * 80];
  const int t = threadIdx.x, w = t >> 6, l = t & 63;
  const int row = l & 15, kg = (l >> 4) * 8;
  if (blockIdx.x < 512) {
    // ---------- sliding path ----------
    u16* sK  = smem;            // 128*72 = 9216
    u16* sVT = smem + 9216;     // 64*136 = 8704
    u16* sP  = smem + 17920;    // 64*136 = 8704
    const int bid = blockIdx.x;
    const int ball = bid & 31, kh = (bid >> 5) & 1, b = bid >> 6;
    const int ks0 = ball * 128;
    size_t kvb = (size_t)(b*2 + kh) * 4096 * 64;
    size_t vtb = (size_t)(b*2 + kh) * 64 * 4096;
    for (int e = t; e < 1024; e += 256) {
      int r = e >> 3, c = (e & 7) * 8;
      *(int4*)&sK[r*72 + c] = *(const int4*)&kr[kvb + (size_t)(ks0 + r)*64 + c];
    }
    for (int e = t; e < 1024; e += 256) {
      int r = e >> 4, ch = e & 15;
      *(int4*)&sVT[r*136 + ch*8] = *(const int4*)&vT[vtb + (size_t)r*4096 + ks0 + ch*8];
    }
    __syncthreads();
    for (int hq = 0; hq < 4; ++hq) {
      int hh = kh*4 + hq;
      for (int qh = 0; qh < 2; ++qh) {
        int qt = ball*2 + qh;
        size_t qbase = ((size_t)(b*8 + hh)*4096 + qt*64) * 64 + (size_t)(w*16 + row)*64;
        bhalf8 a0 = LD8(&qrh[qbase + kg]);
        bhalf8 a1 = LD8(&qrh[qbase + 32 + kg]);
        f32x4 sc[8];
#pragma unroll
        for (int nf = 0; nf < 8; ++nf) sc[nf] = zero4();
#pragma unroll
        for (int kk = 0; kk < 2; ++kk) {
          bhalf8 a = kk ? a1 : a0;
#pragma unroll
          for (int nf = 0; nf < 8; ++nf) {
            bhalf8 bk = LD8(&sK[(nf*16 + row)*72 + kk*32 + kg]);
            sc[nf] = MFMA(a, bk, sc[nf]);
          }
        }
        float mx[4] = {-1e30f, -1e30f, -1e30f, -1e30f};
#pragma unroll
        for (int nf = 0; nf < 8; ++nf)
#pragma unroll
          for (int i = 0; i < 4; ++i) {
            float v = sc[nf][i] * 0.125f;
            sc[nf][i] = v;
            mx[i] = fmaxf(mx[i], v);
          }
#pragma unroll
        for (int i = 0; i < 4; ++i)
#pragma unroll
          for (int o = 1; o < 16; o <<= 1) mx[i] = fmaxf(mx[i], __shfl_xor(mx[i], o));
        float sum[4] = {0.f, 0.f, 0.f, 0.f};
#pragma unroll
        for (int nf = 0; nf < 8; ++nf)
#pragma unroll
          for (int i = 0; i < 4; ++i) {
            float p = expf(sc[nf][i] - mx[i]);
            sc[nf][i] = p;
            sum[i] += p;
          }
#pragma unroll
        for (int i = 0; i < 4; ++i)
#pragma unroll
          for (int o = 1; o < 16; o <<= 1) sum[i] += __shfl_xor(sum[i], o);
        float inv[4];
#pragma unroll
        for (int i = 0; i < 4; ++i) inv[i] = 1.0f / sum[i];
#pragma unroll
        for (int nf = 0; nf < 8; ++nf)
#pragma unroll
          for (int i = 0; i < 4; ++i)
            sP[(w*16 + (l >> 4)*4 + i)*136 + nf*16 + (l & 15)] = f2bf(sc[nf][i] * inv[i]);
        f32x4 ovv[4];
#pragma unroll
        for (int nf = 0; nf < 4; ++nf) ovv[nf] = zero4();
#pragma unroll
        for (int kk = 0; kk < 4; ++kk) {
          bhalf8 a = LD8(&sP[(w*16 + row)*136 + kk*32 + kg]);
#pragma unroll
          for (int nf = 0; nf < 4; ++nf) {
            bhalf8 bv = LD8(&sVT[(nf*16 + row)*136 + kk*32 + kg]);
            ovv[nf] = MFMA(a, bv, ovv[nf]);
          }
        }
#pragma unroll
        for (int i = 0; i < 4; ++i) {
          int q = qt*64 + w*16 + (l >> 4)*4 + i;
          float gate = g32[((size_t)b*4096 + q)*24 + hh*3 + 2];
#pragma unroll
          for (int nf = 0; nf < 4; ++nf) {
            int d = nf*16 + (l & 15);
            size_t oi = (((size_t)b*4096 + q)*8 + hh)*64 + d;
            comb_s[oi] = f2bf(gate * ovv[nf][i]);
          }
        }
      }
    }
  } else {
    // ---------- compressed path ----------
    u16* sKh = smem;            // 80*72 = 5760
    u16* sKl = smem + 5760;     // 5760
    u16* sVT = smem + 11520;    // 64*104 = 6656
    u16* sP  = smem + 18176;    // 64*104 = 6656
    const int bid = blockIdx.x - 512;  // 0..1023
    const int qt = bid & 63, kh = (bid >> 6) & 1, b = bid >> 7;
    size_t kbase = (size_t)(b*2 + kh) * 80 * 64;
    size_t vbase = (size_t)(b*2 + kh) * 64 * 96;
    for (int e = t; e < 640; e += 256) {
      int r = e >> 3, c = (e & 7) * 8;
      *(int4*)&sKh[r*72 + c] = *(const int4*)&ckh[kbase + r*64 + c];
      *(int4*)&sKl[r*72 + c] = *(const int4*)&ckl[kbase + r*64 + c];
    }
    for (int e = t; e < 768; e += 256) {
      int r = e / 12, ch = e % 12;
      *(int4*)&sVT[r*104 + ch*8] = *(const int4*)&cvT[vbase + (size_t)r*96 + ch*8];
    }
    for (int e = l; e < 80; e += 64) sImp[w*80 + e] = 0.f;
#pragma unroll
    for (int i = 0; i < 4; ++i)
      sP[(w*16 + (l & 15))*104 + 80 + (l >> 4)*4 + i] = 0;
    __syncthreads();
    for (int g = 0; g < 4; ++g) {
      size_t qbase = ((size_t)((b*2 + kh)*4 + g)*4096 + qt*64) * 64 + (size_t)(w*16 + row)*64;
      bhalf8 ah0 = LD8(&qrh[qbase + kg]);
      bhalf8 ah1 = LD8(&qrh[qbase + 32 + kg]);
      bhalf8 al0 = LD8(&qrl[qbase + kg]);
      bhalf8 al1 = LD8(&qrl[qbase + 32 + kg]);
      f32x4 sc[5];
#pragma unroll
      for (int nf = 0; nf < 5; ++nf) sc[nf] = zero4();
#pragma unroll
      for (int kk = 0; kk < 2; ++kk) {
        bhalf8 ah = kk ? ah1 : ah0;
        bhalf8 al = kk ? al1 : al0;
#pragma unroll
        for (int nf = 0; nf < 5; ++nf) {
          bhalf8 bh = LD8(&sKh[(nf*16 + row)*72 + kk*32 + kg]);
          bhalf8 bl = LD8(&sKl[(nf*16 + row)*72 + kk*32 + kg]);
          sc[nf] = MFMA(ah, bh, sc[nf]);
          sc[nf] = MFMA(ah, bl, sc[nf]);
          sc[nf] = MFMA(al, bh, sc[nf]);
        }
      }
      float mx[4] = {-1e30f, -1e30f, -1e30f, -1e30f};
#pragma unroll
      for (int nf = 0; nf < 5; ++nf)
#pragma unroll
        for (int i = 0; i < 4; ++i) {
          int col = nf*16 + (l & 15);
          float v = (col < 65) ? sc[nf][i] * 0.125f : -1e30f;
          sc[nf][i] = v;
          mx[i] = fmaxf(mx[i], v);
        }
#pragma unroll
      for (int i = 0; i < 4; ++i)
#pragma unroll
        for (int o = 1; o < 16; o <<= 1) mx[i] = fmaxf(mx[i], __shfl_xor(mx[i], o));
      float sum[4] = {0.f, 0.f, 0.f, 0.f};
#pragma unroll
      for (int nf = 0; nf < 5; ++nf)
#pragma unroll
        for (int i = 0; i < 4; ++i) {
          int col = nf*16 + (l & 15);
          float p = (col < 65) ? expf(sc[nf][i] - mx[i]) : 0.f;
          sc[nf][i] = p;
          sum[i] += p;
        }
#pragma unroll
      for (int i = 0; i < 4; ++i)
#pragma unroll
        for (int o = 1; o < 16; o <<= 1) sum[i] += __shfl_xor(sum[i], o);
      float inv[4];
#pragma unroll
      for (int i = 0; i < 4; ++i) inv[i] = 1.0f / sum[i];
#pragma unroll
      for (int nf = 0; nf < 5; ++nf)
#pragma unroll
        for (int i = 0; i < 4; ++i)
          sP[(w*16 + (l >> 4)*4 + i)*104 + nf*16 + (l & 15)] = f2bf(sc[nf][i] * inv[i]);
#pragma unroll
      for (int nf = 0; nf < 5; ++nf) {
        float cs = 0.f;
#pragma unroll
        for (int i = 0; i < 4; ++i) cs += sc[nf][i] * inv[i];
        cs += __shfl_xor(cs, 16);
        cs += __shfl_xor(cs, 32);
        if (l < 16) sImp[w*80 + nf*16 + l] += cs;
      }
      f32x4 ov[4];
#pragma unroll
      for (int nf = 0; nf < 4; ++nf) ov[nf] = zero4();
#pragma unroll
      for (int kk = 0; kk < 3; ++kk) {
        bhalf8 a = LD8(&sP[(w*16 + row)*104 + kk*32 + kg]);
#pragma unroll
        for (int nf = 0; nf < 4; ++nf) {
          bhalf8 bv = LD8(&sVT[(nf*16 + row)*104 + kk*32 + kg]);
          ov[nf] = MFMA(a, bv, ov[nf]);
        }
      }
      int hq = kh*4 + g;
#pragma unroll
      for (int i = 0; i < 4; ++i) {
        int q = qt*64 + w*16 + (l >> 4)*4 + i;
        float gate = g32[((size_t)b*4096 + q)*24 + hq*3 + 0];
#pragma unroll
        for (int nf = 0; nf < 4; ++nf) {
          int d = nf*16 + (l & 15);
          comb_c[(((size_t)b*4096 + q)*8 + hq)*64 + d] = f2bf(gate * ov[nf][i]);
        }
      }
    }
    __syncthreads();
    if (t < 64) {
      int n = t + 1;
      imp[(size_t)bid*64 + t] = (sImp[n] + sImp[80 + n] + sImp[160 + n] + sImp[240 + n]) * (1.0f/256.0f);
    }
  }
}

// fine: per (b,kh,qblk): inline top-2 (wave 0 from imp); K/VT staged ONCE; Q fragments from
// global; sP wave-private; barrier-free g loop. Final combine: comb_c += comb_s + gate*fine.
__global__ __launch_bounds__(256) void nsa_attn_fine(const u16* __restrict__ qrh, const u16* __restrict__ kr,
    const u16* __restrict__ vT, const float* __restrict__ imp, const float* __restrict__ g32,
    u16* __restrict__ comb_c, const u16* __restrict__ comb_s) {
  __shared__ u16 smem[39424];
  __shared__ int ssel[2];
  u16* sK  = smem;            // 192*72 = 13824
  u16* sVT = smem + 13824;    // 64*200 = 12800
  u16* sP  = smem + 26624;    // 64*200 = 12800
  const int t = threadIdx.x, w = t >> 6, l = t & 63;
  const int bid = blockIdx.x;
  const int qt = bid & 63, kh = (bid >> 6) & 1, b = bid >> 7;
  const int row = l & 15, kg = (l >> 4) * 8;
  if (t < 64) {  // inline top-2 over this block's 64 importance values
    float v = imp[(size_t)bid*64 + t];
    float v1 = v; int i1 = t;
#pragma unroll
    for (int o = 1; o < 64; o <<= 1) {
      float ovv = __shfl_xor(v1, o); int oi = __shfl_xor(i1, o);
      if (ovv > v1 || (ovv == v1 && oi < i1)) { v1 = ovv; i1 = oi; }
    }
    float v2 = (t == i1) ? -3.0e38f : v; int i2 = t;
#pragma unroll
    for (int o = 1; o < 64; o <<= 1) {
      float ovv = __shfl_xor(v2, o); int oi = __shfl_xor(i2, o);
      if (ovv > v2 || (ovv == v2 && oi < i2)) { v2 = ovv; i2 = oi; }
    }
    if (t == 0) { ssel[0] = i1; ssel[1] = i2; }
  }
  __syncthreads();
  const int s0 = ssel[0] & 63, s1 = ssel[1] & 63;
  size_t kvb = (size_t)(b*2 + kh) * 4096 * 64;
  size_t vtb = (size_t)(b*2 + kh) * 64 * 4096;
  for (int e = t; e < 1536; e += 256) {
    int r = e >> 3, c = (e & 7) * 8;
    int bi = r >> 6;
    int blkid = (bi == 0) ? s0 : ((bi == 1) ? s1 : qt);
    int sidx = blkid*64 + (r & 63);
    *(int4*)&sK[r*72 + c] = *(const int4*)&kr[kvb + (size_t)sidx*64 + c];
  }
  for (int e = t; e < 1536; e += 256) {
    int r = e / 24, ch = e % 24;
    int n0 = ch * 8, bi = n0 >> 6;
    int blkid = (bi == 0) ? s0 : ((bi == 1) ? s1 : qt);
    int sidx = blkid*64 + (n0 & 63);
    *(int4*)&sVT[r*200 + n0] = *(const int4*)&vT[vtb + (size_t)r*4096 + sidx];
  }
  __syncthreads();
  for (int g = 0; g < 4; ++g) {
    size_t qbase = ((size_t)((b*2 + kh)*4 + g)*4096 + qt*64) * 64 + (size_t)(w*16 + row)*64;
    bhalf8 a0 = LD8(&qrh[qbase + kg]);
    bhalf8 a1 = LD8(&qrh[qbase + 32 + kg]);
    f32x4 sc[12];
#pragma unroll
    for (int nf = 0; nf < 12; ++nf) sc[nf] = zero4();
#pragma unroll
    for (int kk = 0; kk < 2; ++kk) {
      bhalf8 a = kk ? a1 : a0;
#pragma unroll
      for (int nf = 0; nf < 12; ++nf) {
        bhalf8 bk = LD8(&sK[(nf*16 + row)*72 + kk*32 + kg]);
        sc[nf] = MFMA(a, bk, sc[nf]);
      }
    }
    float mx[4] = {-1e30f, -1e30f, -1e30f, -1e30f};
#pragma unroll
    for (int nf = 0; nf < 12; ++nf)
#pragma unroll
      for (int i = 0; i < 4; ++i) {
        float v = sc[nf][i] * 0.125f;
        sc[nf][i] = v;
        mx[i] = fmaxf(mx[i], v);
      }
#pragma unroll
    for (int i = 0; i < 4; ++i)
#pragma unroll
      for (int o = 1; o < 16; o <<= 1) mx[i] = fmaxf(mx[i], __shfl_xor(mx[i], o));
    float sum[4] = {0.f, 0.f, 0.f, 0.f};
#pragma unroll
    for (int nf = 0; nf < 12; ++nf)
#pragma unroll
      for (int i = 0; i < 4; ++i) {
        float p = expf(sc[nf][i] - mx[i]);
        sc[nf][i] = p;
        sum[i] += p;
      }
#pragma unroll
    for (int i = 0; i < 4; ++i)
#pragma unroll
      for (int o = 1; o < 16; o <<= 1) sum[i] += __shfl_xor(sum[i], o);
    float inv[4];
#pragma unroll
    for (int i = 0; i < 4; ++i) inv[i] = 1.0f / sum[i];
#pragma unroll
    for (int nf = 0; nf < 12; ++nf)
#pragma unroll
      for (int i = 0; i < 4; ++i)
        sP[(w*16 + (l >> 4)*4 + i)*200 + nf*16 + (l & 15)] = f2bf(sc[nf][i] * inv[i]);
    f32x4 ovv[4];
#pragma unroll
    for (int nf = 0; nf < 4; ++nf) ovv[nf] = zero4();
#pragma unroll
    for (int kk = 0; kk < 6; ++kk) {
      bhalf8 a = LD8(&sP[(w*16 + row)*200 + kk*32 + kg]);
#pragma unroll
      for (int nf = 0; nf < 4; ++nf) {
        bhalf8 bv = LD8(&sVT[(nf*16 + row)*200 + kk*32 + kg]);
        ovv[nf] = MFMA(a, bv, ovv[nf]);
      }
    }
    int hq = kh*4 + g;
#pragma unroll
    for (int i = 0; i < 4; ++i) {
      int q = qt*64 + w*16 + (l >> 4)*4 + i;
      float gate = g32[((size_t)b*4096 + q)*24 + hq*3 + 1];
#pragma unroll
      for (int nf = 0; nf < 4; ++nf) {
        int d = nf*16 + (l & 15);
        size_t oi = (((size_t)b*4096 + q)*8 + hq)*64 + d;
        comb_c[oi] = f2bf(bf2f(comb_c[oi]) + bf2f(comb_s[oi]) + gate * ovv[nf][i]);
      }
    }
  }
}

// ================= launch =================

extern "C" void kernel_launch(void* const* d_in, const int* in_sizes, int n_in,
                              void* d_out, int out_size, void* d_ws, size_t ws_size,
                              hipStream_t stream) {
  const float* x     = (const float*)d_in[0];
  const float* pos   = (const float*)d_in[1];
  const float* pe_w  = (const float*)d_in[2];
  const float* pe_b  = (const float*)d_in[3];
  const float* gamma = (const float*)d_in[4];
  const float* wq    = (const float*)d_in[5];
  const float* wk    = (const float*)d_in[6];
  const float* wv    = (const float*)d_in[7];
  const float* k_pos = (const float*)d_in[8];
  const float* v_pos = (const float*)d_in[9];
  const float* k_w1  = (const float*)d_in[10];
  const float* k_b1  = (const float*)d_in[11];
  const float* k_w2  = (const float*)d_in[12];
  const float* k_b2  = (const float*)d_in[13];
  const float* v_w1  = (const float*)d_in[14];
  const float* v_b1  = (const float*)d_in[15];
  const float* v_w2  = (const float*)d_in[16];
  const float* v_b2  = (const float*)d_in[17];
  const float* mem_k = (const float*)d_in[18];
  const float* mem_v = (const float*)d_in[19];
  const float* w_cmb = (const float*)d_in[20];
  const float* w_out = (const float*)d_in[21];
  float* out = (float*)d_out;
  char* ws = (char*)d_ws;

  // ---- region plan (aliased lifetimes), ~244 MiB ----
  size_t off = 0;
  auto A = [&](size_t b) { size_t o = off; off += (b + 255) & ~(size_t)255; return o; };
  const size_t oR1 = A(100663296);  // [h_hi|h_lo|-] -> [w1kh|w1kl|w1vh] -> [comb_c|comb_s|-]
  const size_t oR2 = A(67108864);   // qrh|qrl (live through fine)
  const size_t oR4 = A(16777216);   // th|tl
  const size_t oR5 = A(16777216);   // v16->tv | vbh
  const size_t oR6 = A(16777216);   // kbh|kbl
  const size_t oR7 = A(16777216);   // krb|vT
  const size_t oR8 = A(3145728);    // g32
  const size_t oR9 = A(2097152);    // wch|wcl
  const size_t o_w2 = A(1572864);   // w2h|w2l|w2vh (written in prep kernel, own region)
  const size_t o_cos = A(524288),  o_sin = A(524288);
  const size_t o_ckh = A(163840),  o_ckl = A(163840);
  const size_t o_cvT = A(196608);
  const size_t o_woh = A(524288);
  const size_t o_imp = A(262144);
  const size_t o_part = A(8388608);   // stage-2 partials: k 4MB + v 4MB

  if (ws_size < off) {  // diagnostic: absmax will read ~ws_size in MiB
    nsa_sentinel<<<(out_size + 255)/256, 256, 0, stream>>>(out, out_size, (float)(ws_size >> 20));
    return;
  }

#define WP(T, o) ((T*)(ws + (o)))
  u16*  h_hi = WP(u16, oR1);           u16* h_lo = WP(u16, oR1 + 33554432);
  u16*  w1kh = WP(u16, oR1);           u16* w1kl = WP(u16, oR1 + 33554432);
  u16*  w1vh = WP(u16, oR1 + 67108864);
  u16*  combc = WP(u16, oR1);          // bf16 comb_c (32MB), after w1kh dead
  u16*  combs = WP(u16, oR1 + 33554432);  // bf16 comb_s (32MB), after w1kl dead
  u16*  qrh  = WP(u16, oR2);           u16* qrl  = WP(u16, oR2 + 33554432);
  u16*  th   = WP(u16, oR4);           u16* tl   = WP(u16, oR4 + 8388608);
  u16*  v16b = WP(u16, oR5);           u16* vbh  = WP(u16, oR5 + 8388608);
  u16*  tv   = WP(u16, oR5);           // alias: v16 dead after vT
  u16*  kbh  = WP(u16, oR6);           u16* kbl  = WP(u16, oR6 + 8388608);
  u16*  krb  = WP(u16, oR7);           u16* vTb  = WP(u16, oR7 + 8388608);
  float* g32 = WP(float, oR8);
  u16*  wch  = WP(u16, oR9);           u16* wcl  = WP(u16, oR9 + 917504);
  u16*  w2h  = WP(u16, o_w2);          u16* w2l  = WP(u16, o_w2 + 524288);
  u16*  w2vh = WP(u16, o_w2 + 1048576);
  float* cosb = WP(float, o_cos);      float* sinb = WP(float, o_sin);
  u16*  ckh  = WP(u16, o_ckh);         u16* ckl  = WP(u16, o_ckl);
  u16*  cvT  = WP(u16, o_cvT);
  u16*  woh  = WP(u16, o_woh);
  float* imp = WP(float, o_imp);
  float* part = WP(float, o_part);

  nsa_hnorm<<<32768, 256, 0, stream>>>(x, pos, pe_w, pe_b, gamma, h_hi, h_lo);
  // merged prep: wcat + rope tables + w_out^T + w2^T (all input-only)
  nsa_wcat_rope<<<2496, 256, 0, stream>>>(wq, wk, wv, w_cmb, wch, wcl, cosb, sinb,
      w_out, woh, k_w2, w2h, w2l, v_w2, w2vh);
  // projection: single launch; q/k tiles split, v/gate tiles plain (runtime dsp)
  nsa_gemm<true, 0><<<dim3(256, 7, 1), 256, 0, stream>>>(h_hi, h_lo, wch, wcl, 512, 896,
      cosb, sinb, qrh, qrl, g32, k_pos, v_pos, krb, kbh, kbl, v16b, vbh);
  // merged post-projection: v16 -> vT  +  w1 transposes (k split, v plain; overwrite h)
  nsa_vT_wT<<<9216, 256, 0, stream>>>(v16b, vTb, k_w1, w1kh, w1kl, v_w1, w1vh);
  // merged MLP stage-1 (k split + v plain, fused bias+relu epilogue) [R12-best version]
  nsa_mlp1<<<512, 256, 0, stream>>>(kbh, kbl, vbh, w1kh, w1kl, w1vh, k_b1, v_b1, th, tl, tv);
  // merged stage-2 + reduction
  nsa_gemm64m<<<dim3(16, 32), 256, 0, stream>>>(th, tl, tv, w2h, w2l, w2vh, part);
  nsa_red_ckcv<<<704, 256, 0, stream>>>(part, mem_k, k_b2, mem_v, v_b2, ckh, ckl, cvT);
  // merged comp+slide (slide first), then fine (inline top2 + 3-way combine)
  nsa_attn_cs<<<1536, 256, 0, stream>>>(qrh, qrl, ckh, ckl, cvT, krb, vTb, g32, combc, combs, imp);
  nsa_attn_fine<<<1024, 256, 0, stream>>>(qrh, krb, vTb, imp, g32, combc, combs);
  // output projection (plain bf16, A = comb_c directly)
  nsa_gemm<false, 2><<<dim3(256, 4, 1), 256, 0, stream>>>(combc, nullptr, woh, nullptr, 512, 512,
      nullptr, out, nullptr, nullptr, nullptr, nullptr, nullptr, nullptr, nullptr, nullptr,
      nullptr, nullptr);
#undef WP
}

// Round 16
// 614.331 us; speedup vs baseline: 1.2456x; 1.2456x over previous
//
#include <hip/hip_runtime.h>
#include <stdint.h>

#define DEVI static __device__ __forceinline__
typedef unsigned short u16;
typedef __bf16 bhalf8 __attribute__((ext_vector_type(8)));
typedef float f32x4 __attribute__((ext_vector_type(4)));

DEVI u16 f2bf(float f) {
  union { float f; unsigned u; } v; v.f = f;
  unsigned r = v.u + 0x7FFFu + ((v.u >> 16) & 1u);
  return (u16)(r >> 16);
}
DEVI float bf2f(u16 h) {
  union { unsigned u; float f; } v; v.u = ((unsigned)h) << 16;
  return v.f;
}
DEVI f32x4 MFMA(bhalf8 a, bhalf8 b, f32x4 c) {
  return __builtin_amdgcn_mfma_f32_16x16x32_bf16(a, b, c, 0, 0, 0);
}
DEVI bhalf8 LD8(const u16* p) { return *(const bhalf8*)p; }
DEVI f32x4 zero4() { f32x4 z = {0.f, 0.f, 0.f, 0.f}; return z; }

// async global->LDS, 16B per lane, dest = wave-uniform base + lane*16
#define GLDS16(gp, lp) __builtin_amdgcn_global_load_lds( \
    (const __attribute__((address_space(1))) void*)(gp), \
    (__attribute__((address_space(3))) void*)(lp), 16, 0, 0)

// ================= prep / elementwise =================

__global__ __launch_bounds__(256) void nsa_hnorm(const float* __restrict__ x, const float* __restrict__ pos,
    const float* __restrict__ pew, const float* __restrict__ peb,
    const float* __restrict__ gamma, u16* __restrict__ hhi, u16* __restrict__ hlo) {
  int n = blockIdx.x, t = threadIdx.x;
  int blk = n >> 6;
  __shared__ float spm[3];
  if (t < 64) {
    const float* p = pos + (size_t)(blk * 64 + t) * 3;
    float a = p[0], b = p[1], c = p[2];
#pragma unroll
    for (int o = 32; o; o >>= 1) { a += __shfl_down(a, o); b += __shfl_down(b, o); c += __shfl_down(c, o); }
    if (t == 0) { spm[0] = a * (1.f/64.f); spm[1] = b * (1.f/64.f); spm[2] = c * (1.f/64.f); }
  }
  __syncthreads();
  float r0 = pos[(size_t)n*3+0] - spm[0];
  float r1 = pos[(size_t)n*3+1] - spm[1];
  float r2 = pos[(size_t)n*3+2] - spm[2];
  int c0 = t, c1 = t + 256;
  const float* xr = x + (size_t)n * 512;
  float v0 = xr[c0] + r0*pew[c0] + r1*pew[512+c0] + r2*pew[1024+c0] + peb[c0];
  float v1 = xr[c1] + r0*pew[c1] + r1*pew[512+c1] + r2*pew[1024+c1] + peb[c1];
  float ss = v0*v0 + v1*v1;
#pragma unroll
  for (int o = 32; o; o >>= 1) ss += __shfl_down(ss, o);
  __shared__ float red[4];
  if ((t & 63) == 0) red[t >> 6] = ss;
  __syncthreads();
  float rms = 1.0f / sqrtf((red[0]+red[1]+red[2]+red[3]) * (1.0f/512.0f) + 1e-6f);
  float h0 = v0 * rms * gamma[c0], h1 = v1 * rms * gamma[c1];
  u16 a0 = f2bf(h0); hhi[(size_t)n*512+c0] = a0; hlo[(size_t)n*512+c0] = f2bf(h0 - bf2f(a0));
  u16 a1 = f2bf(h1); hhi[(size_t)n*512+c1] = a1; hlo[(size_t)n*512+c1] = f2bf(h1 - bf2f(a1));
}

// merged prep: [0,1792) WcatT; [1792,2304) rope tables; [2304,2368) w_out^T;
// [2368,2432) k_w2^T (split); [2432,2496) v_w2^T. All input-only -> zero dependencies.
__global__ __launch_bounds__(256) void nsa_wcat_rope(const float* __restrict__ wq, const float* __restrict__ wk,
    const float* __restrict__ wv, const float* __restrict__ wc, u16* __restrict__ hi, u16* __restrict__ lo,
    float* __restrict__ ct, float* __restrict__ st,
    const float* __restrict__ wo, u16* __restrict__ woh,
    const float* __restrict__ kw2, u16* __restrict__ w2h, u16* __restrict__ w2l,
    const float* __restrict__ vw2, u16* __restrict__ w2vh) {
  int bidx = blockIdx.x;
  if (bidx < 1792) {
    int idx = bidx * 256 + threadIdx.x;  // 896*512
    int k = idx & 511, n = idx >> 9;
    float v;
    if (n < 512) v = wq[(size_t)k*512 + n];
    else if (n < 640) v = wk[(size_t)k*128 + n - 512];
    else if (n < 768) v = wv[(size_t)k*128 + n - 640];
    else if (n < 792) v = wc[(size_t)k*24 + n - 768];
    else v = 0.f;
    u16 h = f2bf(v); hi[idx] = h; lo[idx] = f2bf(v - bf2f(h));
  } else if (bidx < 2304) {
    int idx = (bidx - 1792) * 256 + threadIdx.x;  // 4096*32
    int s = idx >> 5, i = idx & 31;
    float e = (float)(2*i) * (1.0f/64.0f);
    float inv = 1.0f / powf(10000.0f, e);
    float f = (float)s * inv;
    ct[idx] = cosf(f); st[idx] = sinf(f);
  } else {
    __shared__ float tile[64][65];
    const float* src; u16* dhi; u16* dlo = nullptr; int K, N, k0, n0;
    if (bidx < 2368) {
      int j = bidx - 2304; src = wo; dhi = woh; K = 512; N = 512;
      k0 = (j & 7) * 64; n0 = (j >> 3) * 64;
    } else if (bidx < 2432) {
      int j = bidx - 2368; src = kw2; dhi = w2h; dlo = w2l; K = 4096; N = 64;
      k0 = j * 64; n0 = 0;
    } else {
      int j = bidx - 2432; src = vw2; dhi = w2vh; K = 4096; N = 64;
      k0 = j * 64; n0 = 0;
    }
    int t = threadIdx.x, r = t >> 2, c0 = (t & 3) * 16;
#pragma unroll
    for (int j = 0; j < 16; ++j) tile[r][c0+j] = src[(size_t)(k0+r)*N + n0 + c0 + j];
    __syncthreads();
    size_t ob = (size_t)(n0 + r)*K + k0 + c0;
    u16 bh[16], bl[16];
#pragma unroll
    for (int j = 0; j < 16; ++j) {
      float v = tile[c0+j][r];
      bh[j] = f2bf(v);
      bl[j] = f2bf(v - bf2f(bh[j]));
    }
    *(int4*)&dhi[ob] = *(int4*)&bh[0];
    *(int4*)&dhi[ob+8] = *(int4*)&bh[8];
    if (dlo) {
      *(int4*)&dlo[ob] = *(int4*)&bl[0];
      *(int4*)&dlo[ob+8] = *(int4*)&bl[8];
    }
  }
}

// v16 (B,KH,S,64 bf16) -> vT (B,KH,64,S bf16), packed int4 stores
__global__ __launch_bounds__(256) void nsa_vT16(const u16* __restrict__ v16, u16* __restrict__ vT) {
  int blk = blockIdx.x;  // (b*2+kh)*64 + chunk
  int st = (blk & 63) * 64, bkh = blk >> 6;
  __shared__ u16 tile[64][72];
  int t = threadIdx.x;
  int s = t >> 2, c0 = (t & 3) * 16;
  const u16* src = v16 + ((size_t)bkh*4096 + st + s) * 64;
  *(int4*)&tile[s][c0]   = *(const int4*)&src[c0];
  *(int4*)&tile[s][c0+8] = *(const int4*)&src[c0+8];
  __syncthreads();
  int d = t >> 2, s0 = (t & 3) * 16;
  u16* dst = vT + ((size_t)bkh*64 + d)*4096 + st + s0;
  u16 buf[16];
#pragma unroll
  for (int j = 0; j < 16; ++j) buf[j] = tile[s0+j][d];
  *(int4*)&dst[0] = *(int4*)&buf[0];
  *(int4*)&dst[8] = *(int4*)&buf[8];
}

// dual transpose via z: z=0 -> (srcA, dhA, dlA), z=1 -> (srcB, dhB, dlB); packed int4 stores
__global__ __launch_bounds__(256) void nsa_wT2(const float* __restrict__ srcA, u16* __restrict__ dhA,
    u16* __restrict__ dlA, const float* __restrict__ srcB, u16* __restrict__ dhB, u16* __restrict__ dlB,
    int K, int N) {
  const float* src = blockIdx.z ? srcB : srcA;
  u16* dhi = blockIdx.z ? dhB : dhA;
  u16* dlo = blockIdx.z ? dlB : dlA;
  __shared__ float tile[64][65];
  int k0 = blockIdx.x * 64, n0 = blockIdx.y * 64;
  int t = threadIdx.x, r = t >> 2, c0 = (t & 3) * 16;
#pragma unroll
  for (int j = 0; j < 16; ++j) tile[r][c0+j] = src[(size_t)(k0+r)*N + n0 + c0 + j];
  __syncthreads();
  size_t ob = (size_t)(n0 + r)*K + k0 + c0;
  u16 bh[16], bl[16];
#pragma unroll
  for (int j = 0; j < 16; ++j) {
    float v = tile[c0+j][r];
    bh[j] = f2bf(v);
    bl[j] = f2bf(v - bf2f(bh[j]));
  }
  *(int4*)&dhi[ob] = *(int4*)&bh[0];
  *(int4*)&dhi[ob+8] = *(int4*)&bh[8];
  if (dlo) {
    *(int4*)&dlo[ob] = *(int4*)&bl[0];
    *(int4*)&dlo[ob+8] = *(int4*)&bl[8];
  }
}

// merged reduce of stage-2 partials: idx<81920 -> ck hi/lo (B,KH,80,64); else cvT (B,KH,64,96)
__global__ __launch_bounds__(256) void nsa_red_ckcv(const float* __restrict__ part,
    const float* __restrict__ mem_k, const float* __restrict__ kb2,
    const float* __restrict__ mem_v, const float* __restrict__ vb2,
    u16* __restrict__ ckh, u16* __restrict__ ckl, u16* __restrict__ cvT) {
  int idx = blockIdx.x * 256 + threadIdx.x;
  if (idx < 81920) {
    int d = idx & 63, n = (idx >> 6) % 80, bkh = idx / (80*64);
    int kh = bkh & 1;
    float v;
    if (n == 0) v = mem_k[kh*64 + d];
    else if (n <= 64) {
      v = kb2[d];
      int m = bkh*64 + (n - 1);
#pragma unroll
      for (int kc = 0; kc < 16; ++kc) v += part[((size_t)kc*1024 + m)*64 + d];
    } else v = 0.f;
    u16 h = f2bf(v); ckh[idx] = h; ckl[idx] = f2bf(v - bf2f(h));
  } else if (idx < 81920 + 98304) {
    int j = idx - 81920;
    int cc = j % 96, d = (j / 96) & 63, bkh = j / (96*64);
    int kh = bkh & 1;
    const float* pv = part + (size_t)16*1024*64;
    float v;
    if (cc == 0) v = mem_v[kh*64 + d];
    else if (cc <= 64) {
      v = vb2[d];
      int m = bkh*64 + (cc - 1);
#pragma unroll
      for (int kc = 0; kc < 16; ++kc) v += pv[((size_t)kc*1024 + m)*64 + d];
    } else v = 0.f;
    cvT[j] = f2bf(v);
  }
}

__global__ __launch_bounds__(256) void nsa_sentinel(float* __restrict__ o, int n, float val) {
  int i = blockIdx.x * 256 + threadIdx.x;
  if (i < n) o[i] = val;
}

// ================= GEMMs =================
// C = A @ B^T. 2-phase dbuf LDS, global_load_lds w16, both-sides XOR swizzle.
// EPI 0 (projection, single launch grid(256,7)): runtime dsp = (n0 <= 512); A-reuse swizzle.
// EPI 2: plain f32 out (p_sin = out), generic XCD swizzle.
template<bool SPLIT, int EPI>
__global__ __launch_bounds__(256) void nsa_gemm(const u16* __restrict__ Ah, const u16* __restrict__ Al,
    const u16* __restrict__ Bh, const u16* __restrict__ Bl, int K, int N,
    const float* __restrict__ p_cos, float* __restrict__ p_sin,
    u16* __restrict__ out_hi, u16* __restrict__ out_lo, float* __restrict__ og,
    const float* __restrict__ kpos, const float* __restrict__ vpos,
    u16* __restrict__ krb, u16* __restrict__ kbh, u16* __restrict__ kbl,
    u16* __restrict__ v16o, u16* __restrict__ vbh) {
  constexpr int NB = SPLIT ? 4 : 2;
  __shared__ u16 sm[NB * 2 * 4096];
  const int t = threadIdx.x, w = t >> 6, l = t & 63;
  const int wm = w >> 1, wn = w & 1;
  int m0, n0;
  if constexpr (EPI == 0) {
    const int nper = (int)gridDim.y;
    const int bid = blockIdx.y * 256 + blockIdx.x;
    const int xcd = bid & 7, j = bid >> 3;
    const int mg = j / (8*nper), rem = j % (8*nper);
    const int nn = rem >> 3, mi = rem & 7;
    m0 = ((xcd * 4 + mg) * 8 + mi) * 128;
    n0 = nn * 128;
  } else {
    const int MBn = gridDim.x;
    const int nwg = MBn * gridDim.y;
    const int bid = blockIdx.y * MBn + blockIdx.x;
    const int swz = (bid & 7) * (nwg >> 3) + (bid >> 3);
    m0 = (swz % MBn) * 128; n0 = (swz / MBn) * 128;
  }
  const bool dsp = SPLIT && (EPI != 0 || n0 <= 512);  // runtime precision per block
  const int row = l & 15;
  const int kc8 = ((l >> 4) ^ ((l >> 1) & 3)) * 8;
  const int gsc = ((l & 3) ^ ((l >> 3) & 3)) * 8;
  const int sr = l >> 2;
  f32x4 acc[4][4];
#pragma unroll
  for (int a = 0; a < 4; ++a)
#pragma unroll
    for (int b = 0; b < 4; ++b) acc[a][b] = zero4();

  auto STAGE = [&](int buf, int k0) {
    u16* base = sm + buf * NB * 4096;
#pragma unroll
    for (int s2 = 0; s2 < 2; ++s2) {
      int seg = w*2 + s2;
      int r = seg*16 + sr;
      size_t ga = (size_t)(m0 + r)*K + k0 + gsc;
      size_t gb = (size_t)(n0 + r)*K + k0 + gsc;
      GLDS16(&Ah[ga], base + seg*512);
      GLDS16(&Bh[gb], base + 4096 + seg*512);
      if (SPLIT && dsp) {
        GLDS16(&Al[ga], base + 2*4096 + seg*512);
        GLDS16(&Bl[gb], base + 3*4096 + seg*512);
      }
    }
  };

  const int nt = K >> 5;
  STAGE(0, 0);
  __syncthreads();
  int cur = 0;
  for (int kt = 0; kt < nt; ++kt) {
    if (kt + 1 < nt) STAGE(cur ^ 1, (kt + 1) * 32);
    u16* bA  = sm + cur * NB * 4096;
    u16* bB  = bA + 4096;
    u16* bAl = bA + 2*4096;
    u16* bBl = bA + 3*4096;
    bhalf8 af[4], afl[4];
#pragma unroll
    for (int mf = 0; mf < 4; ++mf) {
      af[mf] = LD8(&bA[(wm*64 + mf*16 + row)*32 + kc8]);
      if (dsp) afl[mf] = LD8(&bAl[(wm*64 + mf*16 + row)*32 + kc8]);
    }
#pragma unroll
    for (int nf = 0; nf < 4; ++nf) {
      bhalf8 bfh = LD8(&bB[(wn*64 + nf*16 + row)*32 + kc8]);
      bhalf8 bfl;
      if (dsp) bfl = LD8(&bBl[(wn*64 + nf*16 + row)*32 + kc8]);
#pragma unroll
      for (int mf = 0; mf < 4; ++mf) {
        acc[mf][nf] = MFMA(af[mf], bfh, acc[mf][nf]);
        if (dsp) {
          acc[mf][nf] = MFMA(af[mf], bfl, acc[mf][nf]);
          acc[mf][nf] = MFMA(afl[mf], bfh, acc[mf][nf]);
        }
      }
    }
    __syncthreads();
    cur ^= 1;
  }
  if constexpr (EPI == 0) {
    if (n0 < 512) {
      // q columns: fused GPT-NeoX rotary. cols c (dd<32) pair with c+32 = acc[mf][nf+2].
#pragma unroll
      for (int mf = 0; mf < 4; ++mf)
#pragma unroll
        for (int i = 0; i < 4; ++i) {
          int r = m0 + wm*64 + mf*16 + (l >> 4)*4 + i;
          int s = r & 4095, b = r >> 12;
#pragma unroll
          for (int nf = 0; nf < 2; ++nf) {
            int c = n0 + wn*64 + nf*16 + (l & 15);
            int hq = c >> 6, dd = c & 31;
            float t1 = acc[mf][nf][i], t2 = acc[mf][nf+2][i];
            float cs = p_cos[s*32 + dd], sn = p_sin[s*32 + dd];
            float o1 = t1*cs - t2*sn, o2 = t2*cs + t1*sn;
            size_t ob = (((size_t)(b*8 + hq))*4096 + s)*64;
            u16 h1 = f2bf(o1); out_hi[ob+dd] = h1;    out_lo[ob+dd] = f2bf(o1 - bf2f(h1));
            u16 h2 = f2bf(o2); out_hi[ob+dd+32] = h2; out_lo[ob+dd+32] = f2bf(o2 - bf2f(h2));
          }
        }
    } else if (n0 == 512) {
      // k columns: fused rotary -> krb; (k + k_pos) split -> kbh/kbl
      int kh = wn;
#pragma unroll
      for (int mf = 0; mf < 4; ++mf)
#pragma unroll
        for (int i = 0; i < 4; ++i) {
          int r = m0 + wm*64 + mf*16 + (l >> 4)*4 + i;
          int s = r & 4095, b = r >> 12;
          int n = s >> 6, sl = s & 63;
          size_t krbase = ((size_t)(b*2 + kh)*4096 + s)*64;
          size_t kbbase = ((size_t)(b*128 + kh*64 + n))*4096 + sl*64;
#pragma unroll
          for (int nf = 0; nf < 2; ++nf) {
            int dd = nf*16 + (l & 15);
            float t1 = acc[mf][nf][i], t2 = acc[mf][nf+2][i];
            float cs = p_cos[s*32 + dd], sn = p_sin[s*32 + dd];
            krb[krbase + dd]      = f2bf(t1*cs - t2*sn);
            krb[krbase + dd + 32] = f2bf(t2*cs + t1*sn);
          }
#pragma unroll
          for (int nf = 0; nf < 4; ++nf) {
            int dk = nf*16 + (l & 15);
            float v = acc[mf][nf][i] + kpos[(kh*64 + sl)*64 + dk];
            u16 h = f2bf(v);
            kbh[kbbase + dk] = h;
            kbl[kbbase + dk] = f2bf(v - bf2f(h));
          }
        }
    } else if (n0 == 640) {
      // v columns: v16 bf16 + (v + v_pos) -> vbh (plain)
      int kh = wn;
#pragma unroll
      for (int mf = 0; mf < 4; ++mf)
#pragma unroll
        for (int i = 0; i < 4; ++i) {
          int r = m0 + wm*64 + mf*16 + (l >> 4)*4 + i;
          int s = r & 4095, b = r >> 12;
          int n = s >> 6, sl = s & 63;
          size_t v16base = ((size_t)(b*2 + kh)*4096 + s)*64;
          size_t vbbase = ((size_t)(b*128 + kh*64 + n))*4096 + sl*64;
#pragma unroll
          for (int nf = 0; nf < 4; ++nf) {
            int dv = nf*16 + (l & 15);
            float vv = acc[mf][nf][i];
            v16o[v16base + dv] = f2bf(vv);
            vbh[vbbase + dv] = f2bf(vv + vpos[(kh*64 + sl)*64 + dv]);
          }
        }
    } else {
#pragma unroll
      for (int mf = 0; mf < 4; ++mf)
#pragma unroll
        for (int nf = 0; nf < 4; ++nf)
#pragma unroll
          for (int i = 0; i < 4; ++i) {
            int r = m0 + wm*64 + mf*16 + (l >> 4)*4 + i;
            int c = n0 + wn*64 + nf*16 + (l & 15);
            if (c < 792) og[(size_t)r*24 + (c - 768)] = 1.0f / (1.0f + expf(-acc[mf][nf][i]));
          }
    }
  } else {  // EPI == 2
#pragma unroll
    for (int mf = 0; mf < 4; ++mf)
#pragma unroll
      for (int nf = 0; nf < 4; ++nf)
#pragma unroll
        for (int i = 0; i < 4; ++i) {
          int r = m0 + wm*64 + mf*16 + (l >> 4)*4 + i;
          int c = n0 + wn*64 + nf*16 + (l & 15);
          p_sin[(size_t)r*N + c] = acc[mf][nf][i];
        }
  }
}

// merged MLP stage-1 (R12-measured-best): grid 512. Block u<32 -> k (split, 3 MFMA, out th/tl);
// u>=32 -> v (plain, out tv). Per-XCD: 4 k-coltiles + 4 v-coltiles, m-minor. Fused bias+relu.
__global__ __launch_bounds__(256) void nsa_mlp1(const u16* __restrict__ kbh, const u16* __restrict__ kbl,
    const u16* __restrict__ vbh, const u16* __restrict__ w1kh, const u16* __restrict__ w1kl,
    const u16* __restrict__ w1vh, const float* __restrict__ kb1, const float* __restrict__ vb1,
    u16* __restrict__ th, u16* __restrict__ tl, u16* __restrict__ tv) {
  __shared__ u16 sm[4 * 2 * 4096];  // 64KB
  const int t = threadIdx.x, w = t >> 6, l = t & 63;
  const int wm = w >> 1, wn = w & 1;
  const int bid = blockIdx.x;
  const int xcd = bid & 7, u = bid >> 3;
  const bool isK = u < 32;
  const int uu = isK ? u : u - 32;
  const int m0 = (uu & 7) * 128;
  const int n0 = (xcd * 4 + (uu >> 3)) * 128;
  const u16* Ah = isK ? kbh : vbh;
  const u16* Bh = isK ? w1kh : w1vh;
  constexpr int K = 4096;
  const int row = l & 15;
  const int kc8 = ((l >> 4) ^ ((l >> 1) & 3)) * 8;
  const int gsc = ((l & 3) ^ ((l >> 3) & 3)) * 8;
  const int sr = l >> 2;
  f32x4 acc[4][4];
#pragma unroll
  for (int a = 0; a < 4; ++a)
#pragma unroll
    for (int b = 0; b < 4; ++b) acc[a][b] = zero4();

  auto STAGE = [&](int buf, int k0) {
    u16* base = sm + buf * 4 * 4096;
#pragma unroll
    for (int s2 = 0; s2 < 2; ++s2) {
      int seg = w*2 + s2;
      int r = seg*16 + sr;
      size_t ga = (size_t)(m0 + r)*K + k0 + gsc;
      size_t gb = (size_t)(n0 + r)*K + k0 + gsc;
      GLDS16(&Ah[ga], base + seg*512);
      GLDS16(&Bh[gb], base + 4096 + seg*512);
      if (isK) {
        GLDS16(&kbl[ga], base + 2*4096 + seg*512);
        GLDS16(&w1kl[gb], base + 3*4096 + seg*512);
      }
    }
  };

  STAGE(0, 0);
  __syncthreads();
  int cur = 0;
  for (int kt = 0; kt < 128; ++kt) {
    if (kt + 1 < 128) STAGE(cur ^ 1, (kt + 1) * 32);
    u16* bA  = sm + cur * 4 * 4096;
    u16* bB  = bA + 4096;
    u16* bAl = bA + 2*4096;
    u16* bBl = bA + 3*4096;
    bhalf8 af[4], afl[4];
#pragma unroll
    for (int mf = 0; mf < 4; ++mf) {
      af[mf] = LD8(&bA[(wm*64 + mf*16 + row)*32 + kc8]);
      if (isK) afl[mf] = LD8(&bAl[(wm*64 + mf*16 + row)*32 + kc8]);
    }
#pragma unroll
    for (int nf = 0; nf < 4; ++nf) {
      bhalf8 bfh = LD8(&bB[(wn*64 + nf*16 + row)*32 + kc8]);
      bhalf8 bfl;
      if (isK) bfl = LD8(&bBl[(wn*64 + nf*16 + row)*32 + kc8]);
#pragma unroll
      for (int mf = 0; mf < 4; ++mf) {
        acc[mf][nf] = MFMA(af[mf], bfh, acc[mf][nf]);
        if (isK) {
          acc[mf][nf] = MFMA(af[mf], bfl, acc[mf][nf]);
          acc[mf][nf] = MFMA(afl[mf], bfh, acc[mf][nf]);
        }
      }
    }
    __syncthreads();
    cur ^= 1;
  }
  const float* bias = isK ? kb1 : vb1;
#pragma unroll
  for (int mf = 0; mf < 4; ++mf)
#pragma unroll
    for (int nf = 0; nf < 4; ++nf)
#pragma unroll
      for (int i = 0; i < 4; ++i) {
        int r = m0 + wm*64 + mf*16 + (l >> 4)*4 + i;
        int c = n0 + wn*64 + nf*16 + (l & 15);
        float v = fmaxf(acc[mf][nf][i] + bias[c], 0.f);
        if (isK) {
          u16 h = f2bf(v);
          th[(size_t)r*4096 + c] = h;
          tl[(size_t)r*4096 + c] = f2bf(v - bf2f(h));
        } else {
          tv[(size_t)r*4096 + c] = f2bf(v);
        }
      }
}

// merged stage-2: grid (16,32). y<16 -> k (split, A=th/tl, B=w2h/w2l); y>=16 -> v (plain).
// 16 K-slices of 256 each -> deterministic partials.
__global__ __launch_bounds__(256) void nsa_gemm64m(const u16* __restrict__ th, const u16* __restrict__ tl,
    const u16* __restrict__ tv, const u16* __restrict__ w2h, const u16* __restrict__ w2l,
    const u16* __restrict__ w2vh, float* __restrict__ part) {
  __shared__ u16 sm[4 * 2 * 2048];  // 32KB
  const int t = threadIdx.x, w = t >> 6, l = t & 63;
  const int mt = blockIdx.x;
  const bool isK = blockIdx.y < 16;
  const int kc = blockIdx.y & 15;
  const u16* Ah = isK ? th : tv;
  const u16* Bh = isK ? w2h : w2vh;
  float* po = part + (isK ? 0 : (size_t)16*1024*64);
  const int row = l & 15;
  const int kc8 = ((l >> 4) ^ ((l >> 1) & 3)) * 8;
  const int gsc = ((l & 3) ^ ((l >> 3) & 3)) * 8;
  const int sr = l >> 2;
  f32x4 acc[4];
#pragma unroll
  for (int a = 0; a < 4; ++a) acc[a] = zero4();

  auto STAGE = [&](int buf, int k0) {
    u16* base = sm + buf * 4 * 2048;
    int r = w*16 + sr;
    size_t ga = (size_t)(mt*64 + r)*4096 + k0 + gsc;
    size_t gb = (size_t)r*4096 + k0 + gsc;
    GLDS16(&Ah[ga], base + w*512);
    GLDS16(&Bh[gb], base + 2048 + w*512);
    if (isK) {
      GLDS16(&tl[ga], base + 2*2048 + w*512);
      GLDS16(&w2l[gb], base + 3*2048 + w*512);
    }
  };

  STAGE(0, kc*256);
  __syncthreads();
  int cur = 0;
  for (int kt = 0; kt < 8; ++kt) {
    if (kt + 1 < 8) STAGE(cur ^ 1, kc*256 + (kt + 1) * 32);
    u16* bA  = sm + cur * 4 * 2048;
    u16* bB  = bA + 2048;
    u16* bAl = bA + 2*2048;
    u16* bBl = bA + 3*2048;
    bhalf8 a = LD8(&bA[(w*16 + row)*32 + kc8]);
    bhalf8 al;
    if (isK) al = LD8(&bAl[(w*16 + row)*32 + kc8]);
#pragma unroll
    for (int nf = 0; nf < 4; ++nf) {
      bhalf8 b = LD8(&bB[(nf*16 + row)*32 + kc8]);
      bhalf8 bl;
      if (isK) bl = LD8(&bBl[(nf*16 + row)*32 + kc8]);
      acc[nf] = MFMA(a, b, acc[nf]);
      if (isK) {
        acc[nf] = MFMA(a, bl, acc[nf]);
        acc[nf] = MFMA(al, b, acc[nf]);
      }
    }
    __syncthreads();
    cur ^= 1;
  }
#pragma unroll
  for (int nf = 0; nf < 4; ++nf)
#pragma unroll
    for (int i = 0; i < 4; ++i) {
      int m = mt*64 + w*16 + (l >> 4)*4 + i;
      int d = nf*16 + (l & 15);
      po[((size_t)kc*1024 + m)*64 + d] = acc[nf][i];
    }
}

// ================= attention =================

// merged comp+slide: blocks [0,512) = slide (writes comb_s); [512,1536) = comp (writes comb_c + imp).
__global__ __launch_bounds__(256) void nsa_attn_cs(const u16* __restrict__ qrh, const u16* __restrict__ qrl,
    const u16* __restrict__ ckh, const u16* __restrict__ ckl, const u16* __restrict__ cvT,
    const u16* __restrict__ kr, const u16* __restrict__ vT, const float* __restrict__ g32,
    u16* __restrict__ comb_c, u16* __restrict__ comb_s, float* __restrict__ imp) {
  __shared__ u16 smem[26624];
  __shared__ float sImp[4 * 80];
  const int t = threadIdx.x, w = t >> 6, l = t & 63;
  const int row = l & 15, kg = (l >> 4) * 8;
  if (blockIdx.x < 512) {
    // ---------- sliding path ----------
    u16* sK  = smem;            // 128*72 = 9216
    u16* sVT = smem + 9216;     // 64*136 = 8704
    u16* sP  = smem + 17920;    // 64*136 = 8704
    const int bid = blockIdx.x;
    const int ball = bid & 31, kh = (bid >> 5) & 1, b = bid >> 6;
    const int ks0 = ball * 128;
    size_t kvb = (size_t)(b*2 + kh) * 4096 * 64;
    size_t vtb = (size_t)(b*2 + kh) * 64 * 4096;
    for (int e = t; e < 1024; e += 256) {
      int r = e >> 3, c = (e & 7) * 8;
      *(int4*)&sK[r*72 + c] = *(const int4*)&kr[kvb + (size_t)(ks0 + r)*64 + c];
    }
    for (int e = t; e < 1024; e += 256) {
      int r = e >> 4, ch = e & 15;
      *(int4*)&sVT[r*136 + ch*8] = *(const int4*)&vT[vtb + (size_t)r*4096 + ks0 + ch*8];
    }
    __syncthreads();
    for (int hq = 0; hq < 4; ++hq) {
      int hh = kh*4 + hq;
      for (int qh = 0; qh < 2; ++qh) {
        int qt = ball*2 + qh;
        size_t qbase = ((size_t)(b*8 + hh)*4096 + qt*64) * 64 + (size_t)(w*16 + row)*64;
        bhalf8 a0 = LD8(&qrh[qbase + kg]);
        bhalf8 a1 = LD8(&qrh[qbase + 32 + kg]);
        f32x4 sc[8];
#pragma unroll
        for (int nf = 0; nf < 8; ++nf) sc[nf] = zero4();
#pragma unroll
        for (int kk = 0; kk < 2; ++kk) {
          bhalf8 a = kk ? a1 : a0;
#pragma unroll
          for (int nf = 0; nf < 8; ++nf) {
            bhalf8 bk = LD8(&sK[(nf*16 + row)*72 + kk*32 + kg]);
            sc[nf] = MFMA(a, bk, sc[nf]);
          }
        }
        float mx[4] = {-1e30f, -1e30f, -1e30f, -1e30f};
#pragma unroll
        for (int nf = 0; nf < 8; ++nf)
#pragma unroll
          for (int i = 0; i < 4; ++i) {
            float v = sc[nf][i] * 0.125f;
            sc[nf][i] = v;
            mx[i] = fmaxf(mx[i], v);
          }
#pragma unroll
        for (int i = 0; i < 4; ++i)
#pragma unroll
          for (int o = 1; o < 16; o <<= 1) mx[i] = fmaxf(mx[i], __shfl_xor(mx[i], o));
        float sum[4] = {0.f, 0.f, 0.f, 0.f};
#pragma unroll
        for (int nf = 0; nf < 8; ++nf)
#pragma unroll
          for (int i = 0; i < 4; ++i) {
            float p = expf(sc[nf][i] - mx[i]);
            sc[nf][i] = p;
            sum[i] += p;
          }
#pragma unroll
        for (int i = 0; i < 4; ++i)
#pragma unroll
          for (int o = 1; o < 16; o <<= 1) sum[i] += __shfl_xor(sum[i], o);
        float inv[4];
#pragma unroll
        for (int i = 0; i < 4; ++i) inv[i] = 1.0f / sum[i];
#pragma unroll
        for (int nf = 0; nf < 8; ++nf)
#pragma unroll
          for (int i = 0; i < 4; ++i)
            sP[(w*16 + (l >> 4)*4 + i)*136 + nf*16 + (l & 15)] = f2bf(sc[nf][i] * inv[i]);
        f32x4 ovv[4];
#pragma unroll
        for (int nf = 0; nf < 4; ++nf) ovv[nf] = zero4();
#pragma unroll
        for (int kk = 0; kk < 4; ++kk) {
          bhalf8 a = LD8(&sP[(w*16 + row)*136 + kk*32 + kg]);
#pragma unroll
          for (int nf = 0; nf < 4; ++nf) {
            bhalf8 bv = LD8(&sVT[(nf*16 + row)*136 + kk*32 + kg]);
            ovv[nf] = MFMA(a, bv, ovv[nf]);
          }
        }
#pragma unroll
        for (int i = 0; i < 4; ++i) {
          int q = qt*64 + w*16 + (l >> 4)*4 + i;
          float gate = g32[((size_t)b*4096 + q)*24 + hh*3 + 2];
#pragma unroll
          for (int nf = 0; nf < 4; ++nf) {
            int d = nf*16 + (l & 15);
            size_t oi = (((size_t)b*4096 + q)*8 + hh)*64 + d;
            comb_s[oi] = f2bf(gate * ovv[nf][i]);
          }
        }
      }
    }
  } else {
    // ---------- compressed path ----------
    u16* sKh = smem;            // 80*72 = 5760
    u16* sKl = smem + 5760;     // 5760
    u16* sVT = smem + 11520;    // 64*104 = 6656
    u16* sP  = smem + 18176;    // 64*104 = 6656
    const int bid = blockIdx.x - 512;  // 0..1023
    const int qt = bid & 63, kh = (bid >> 6) & 1, b = bid >> 7;
    size_t kbase = (size_t)(b*2 + kh) * 80 * 64;
    size_t vbase = (size_t)(b*2 + kh) * 64 * 96;
    for (int e = t; e < 640; e += 256) {
      int r = e >> 3, c = (e & 7) * 8;
      *(int4*)&sKh[r*72 + c] = *(const int4*)&ckh[kbase + r*64 + c];
      *(int4*)&sKl[r*72 + c] = *(const int4*)&ckl[kbase + r*64 + c];
    }
    for (int e = t; e < 768; e += 256) {
      int r = e / 12, ch = e % 12;
      *(int4*)&sVT[r*104 + ch*8] = *(const int4*)&cvT[vbase + (size_t)r*96 + ch*8];
    }
    for (int e = l; e < 80; e += 64) sImp[w*80 + e] = 0.f;
#pragma unroll
    for (int i = 0; i < 4; ++i)
      sP[(w*16 + (l & 15))*104 + 80 + (l >> 4)*4 + i] = 0;
    __syncthreads();
    for (int g = 0; g < 4; ++g) {
      size_t qbase = ((size_t)((b*2 + kh)*4 + g)*4096 + qt*64) * 64 + (size_t)(w*16 + row)*64;
      bhalf8 ah0 = LD8(&qrh[qbase + kg]);
      bhalf8 ah1 = LD8(&qrh[qbase + 32 + kg]);
      bhalf8 al0 = LD8(&qrl[qbase + kg]);
      bhalf8 al1 = LD8(&qrl[qbase + 32 + kg]);
      f32x4 sc[5];
#pragma unroll
      for (int nf = 0; nf < 5; ++nf) sc[nf] = zero4();
#pragma unroll
      for (int kk = 0; kk < 2; ++kk) {
        bhalf8 ah = kk ? ah1 : ah0;
        bhalf8 al = kk ? al1 : al0;
#pragma unroll
        for (int nf = 0; nf < 5; ++nf) {
          bhalf8 bh = LD8(&sKh[(nf*16 + row)*72 + kk*32 + kg]);
          bhalf8 bl = LD8(&sKl[(nf*16 + row)*72 + kk*32 + kg]);
          sc[nf] = MFMA(ah, bh, sc[nf]);
          sc[nf] = MFMA(ah, bl, sc[nf]);
          sc[nf] = MFMA(al, bh, sc[nf]);
        }
      }
      float mx[4] = {-1e30f, -1e30f, -1e30f, -1e30f};
#pragma unroll
      for (int nf = 0; nf < 5; ++nf)
#pragma unroll
        for (int i = 0; i < 4; ++i) {
          int col = nf*16 + (l & 15);
          float v = (col < 65) ? sc[nf][i] * 0.125f : -1e30f;
          sc[nf][i] = v;
          mx[i] = fmaxf(mx[i], v);
        }
#pragma unroll
      for (int i = 0; i < 4; ++i)
#pragma unroll
        for (int o = 1; o < 16; o <<= 1) mx[i] = fmaxf(mx[i], __shfl_xor(mx[i], o));
      float sum[4] = {0.f, 0.f, 0.f, 0.f};
#pragma unroll
      for (int nf = 0; nf < 5; ++nf)
#pragma unroll
        for (int i = 0; i < 4; ++i) {
          int col = nf*16 + (l & 15);
          float p = (col < 65) ? expf(sc[nf][i] - mx[i]) : 0.f;
          sc[nf][i] = p;
          sum[i] += p;
        }
#pragma unroll
      for (int i = 0; i < 4; ++i)
#pragma unroll
        for (int o = 1; o < 16; o <<= 1) sum[i] += __shfl_xor(sum[i], o);
      float inv[4];
#pragma unroll
      for (int i = 0; i < 4; ++i) inv[i] = 1.0f / sum[i];
#pragma unroll
      for (int nf = 0; nf < 5; ++nf)
#pragma unroll
        for (int i = 0; i < 4; ++i)
          sP[(w*16 + (l >> 4)*4 + i)*104 + nf*16 + (l & 15)] = f2bf(sc[nf][i] * inv[i]);
#pragma unroll
      for (int nf = 0; nf < 5; ++nf) {
        float cs = 0.f;
#pragma unroll
        for (int i = 0; i < 4; ++i) cs += sc[nf][i] * inv[i];
        cs += __shfl_xor(cs, 16);
        cs += __shfl_xor(cs, 32);
        if (l < 16) sImp[w*80 + nf*16 + l] += cs;
      }
      f32x4 ov[4];
#pragma unroll
      for (int nf = 0; nf < 4; ++nf) ov[nf] = zero4();
#pragma unroll
      for (int kk = 0; kk < 3; ++kk) {
        bhalf8 a = LD8(&sP[(w*16 + row)*104 + kk*32 + kg]);
#pragma unroll
        for (int nf = 0; nf < 4; ++nf) {
          bhalf8 bv = LD8(&sVT[(nf*16 + row)*104 + kk*32 + kg]);
          ov[nf] = MFMA(a, bv, ov[nf]);
        }
      }
      int hq = kh*4 + g;
#pragma unroll
      for (int i = 0; i < 4; ++i) {
        int q = qt*64 + w*16 + (l >> 4)*4 + i;
        float gate = g32[((size_t)b*4096 + q)*24 + hq*3 + 0];
#pragma unroll
        for (int nf = 0; nf < 4; ++nf) {
          int d = nf*16 + (l & 15);
          comb_c[(((size_t)b*4096 + q)*8 + hq)*64 + d] = f2bf(gate * ov[nf][i]);
        }
      }
    }
    __syncthreads();
    if (t < 64) {
      int n = t + 1;
      imp[(size_t)bid*64 + t] = (sImp[n] + sImp[80 + n] + sImp[160 + n] + sImp[240 + n]) * (1.0f/256.0f);
    }
  }
}

// fine: per (b,kh,qblk): inline top-2 (wave 0 from imp); K/VT staged ONCE; Q fragments from
// global; sP wave-private; barrier-free g loop. Final combine: comb_c += comb_s + gate*fine.
__global__ __launch_bounds__(256) void nsa_attn_fine(const u16* __restrict__ qrh, const u16* __restrict__ kr,
    const u16* __restrict__ vT, const float* __restrict__ imp, const float* __restrict__ g32,
    u16* __restrict__ comb_c, const u16* __restrict__ comb_s) {
  __shared__ u16 smem[39424];
  __shared__ int ssel[2];
  u16* sK  = smem;            // 192*72 = 13824
  u16* sVT = smem + 13824;    // 64*200 = 12800
  u16* sP  = smem + 26624;    // 64*200 = 12800
  const int t = threadIdx.x, w = t >> 6, l = t & 63;
  const int bid = blockIdx.x;
  const int qt = bid & 63, kh = (bid >> 6) & 1, b = bid >> 7;
  const int row = l & 15, kg = (l >> 4) * 8;
  if (t < 64) {  // inline top-2 over this block's 64 importance values
    float v = imp[(size_t)bid*64 + t];
    float v1 = v; int i1 = t;
#pragma unroll
    for (int o = 1; o < 64; o <<= 1) {
      float ovv = __shfl_xor(v1, o); int oi = __shfl_xor(i1, o);
      if (ovv > v1 || (ovv == v1 && oi < i1)) { v1 = ovv; i1 = oi; }
    }
    float v2 = (t == i1) ? -3.0e38f : v; int i2 = t;
#pragma unroll
    for (int o = 1; o < 64; o <<= 1) {
      float ovv = __shfl_xor(v2, o); int oi = __shfl_xor(i2, o);
      if (ovv > v2 || (ovv == v2 && oi < i2)) { v2 = ovv; i2 = oi; }
    }
    if (t == 0) { ssel[0] = i1; ssel[1] = i2; }
  }
  __syncthreads();
  const int s0 = ssel[0] & 63, s1 = ssel[1] & 63;
  size_t kvb = (size_t)(b*2 + kh) * 4096 * 64;
  size_t vtb = (size_t)(b*2 + kh) * 64 * 4096;
  for (int e = t; e < 1536; e += 256) {
    int r = e >> 3, c = (e & 7) * 8;
    int bi = r >> 6;
    int blkid = (bi == 0) ? s0 : ((bi == 1) ? s1 : qt);
    int sidx = blkid*64 + (r & 63);
    *(int4*)&sK[r*72 + c] = *(const int4*)&kr[kvb + (size_t)sidx*64 + c];
  }
  for (int e = t; e < 1536; e += 256) {
    int r = e / 24, ch = e % 24;
    int n0 = ch * 8, bi = n0 >> 6;
    int blkid = (bi == 0) ? s0 : ((bi == 1) ? s1 : qt);
    int sidx = blkid*64 + (n0 & 63);
    *(int4*)&sVT[r*200 + n0] = *(const int4*)&vT[vtb + (size_t)r*4096 + sidx];
  }
  __syncthreads();
  for (int g = 0; g < 4; ++g) {
    size_t qbase = ((size_t)((b*2 + kh)*4 + g)*4096 + qt*64) * 64 + (size_t)(w*16 + row)*64;
    bhalf8 a0 = LD8(&qrh[qbase + kg]);
    bhalf8 a1 = LD8(&qrh[qbase + 32 + kg]);
    f32x4 sc[12];
#pragma unroll
    for (int nf = 0; nf < 12; ++nf) sc[nf] = zero4();
#pragma unroll
    for (int kk = 0; kk < 2; ++kk) {
      bhalf8 a = kk ? a1 : a0;
#pragma unroll
      for (int nf = 0; nf < 12; ++nf) {
        bhalf8 bk = LD8(&sK[(nf*16 + row)*72 + kk*32 + kg]);
        sc[nf] = MFMA(a, bk, sc[nf]);
      }
    }
    float mx[4] = {-1e30f, -1e30f, -1e30f, -1e30f};
#pragma unroll
    for (int nf = 0; nf < 12; ++nf)
#pragma unroll
      for (int i = 0; i < 4; ++i) {
        float v = sc[nf][i] * 0.125f;
        sc[nf][i] = v;
        mx[i] = fmaxf(mx[i], v);
      }
#pragma unroll
    for (int i = 0; i < 4; ++i)
#pragma unroll
      for (int o = 1; o < 16; o <<= 1) mx[i] = fmaxf(mx[i], __shfl_xor(mx[i], o));
    float sum[4] = {0.f, 0.f, 0.f, 0.f};
#pragma unroll
    for (int nf = 0; nf < 12; ++nf)
#pragma unroll
      for (int i = 0; i < 4; ++i) {
        float p = expf(sc[nf][i] - mx[i]);
        sc[nf][i] = p;
        sum[i] += p;
      }
#pragma unroll
    for (int i = 0; i < 4; ++i)
#pragma unroll
      for (int o = 1; o < 16; o <<= 1) sum[i] += __shfl_xor(sum[i], o);
    float inv[4];
#pragma unroll
    for (int i = 0; i < 4; ++i) inv[i] = 1.0f / sum[i];
#pragma unroll
    for (int nf = 0; nf < 12; ++nf)
#pragma unroll
      for (int i = 0; i < 4; ++i)
        sP[(w*16 + (l >> 4)*4 + i)*200 + nf*16 + (l & 15)] = f2bf(sc[nf][i] * inv[i]);
    f32x4 ovv[4];
#pragma unroll
    for (int nf = 0; nf < 4; ++nf) ovv[nf] = zero4();
#pragma unroll
    for (int kk = 0; kk < 6; ++kk) {
      bhalf8 a = LD8(&sP[(w*16 + row)*200 + kk*32 + kg]);
#pragma unroll
      for (int nf = 0; nf < 4; ++nf) {
        bhalf8 bv = LD8(&sVT[(nf*16 + row)*200 + kk*32 + kg]);
        ovv[nf] = MFMA(a, bv, ovv[nf]);
      }
    }
    int hq = kh*4 + g;
#pragma unroll
    for (int i = 0; i < 4; ++i) {
      int q = qt*64 + w*16 + (l >> 4)*4 + i;
      float gate = g32[((size_t)b*4096 + q)*24 + hq*3 + 1];
#pragma unroll
      for (int nf = 0; nf < 4; ++nf) {
        int d = nf*16 + (l & 15);
        size_t oi = (((size_t)b*4096 + q)*8 + hq)*64 + d;
        comb_c[oi] = f2bf(bf2f(comb_c[oi]) + bf2f(comb_s[oi]) + gate * ovv[nf][i]);
      }
    }
  }
}

// ================= launch =================

extern "C" void kernel_launch(void* const* d_in, const int* in_sizes, int n_in,
                              void* d_out, int out_size, void* d_ws, size_t ws_size,
                              hipStream_t stream) {
  const float* x     = (const float*)d_in[0];
  const float* pos   = (const float*)d_in[1];
  const float* pe_w  = (const float*)d_in[2];
  const float* pe_b  = (const float*)d_in[3];
  const float* gamma = (const float*)d_in[4];
  const float* wq    = (const float*)d_in[5];
  const float* wk    = (const float*)d_in[6];
  const float* wv    = (const float*)d_in[7];
  const float* k_pos = (const float*)d_in[8];
  const float* v_pos = (const float*)d_in[9];
  const float* k_w1  = (const float*)d_in[10];
  const float* k_b1  = (const float*)d_in[11];
  const float* k_w2  = (const float*)d_in[12];
  const float* k_b2  = (const float*)d_in[13];
  const float* v_w1  = (const float*)d_in[14];
  const float* v_b1  = (const float*)d_in[15];
  const float* v_w2  = (const float*)d_in[16];
  const float* v_b2  = (const float*)d_in[17];
  const float* mem_k = (const float*)d_in[18];
  const float* mem_v = (const float*)d_in[19];
  const float* w_cmb = (const float*)d_in[20];
  const float* w_out = (const float*)d_in[21];
  float* out = (float*)d_out;
  char* ws = (char*)d_ws;

  // ---- region plan (aliased lifetimes), ~244 MiB ----
  size_t off = 0;
  auto A = [&](size_t b) { size_t o = off; off += (b + 255) & ~(size_t)255; return o; };
  const size_t oR1 = A(100663296);  // [h_hi|h_lo|-] -> [w1kh|w1kl|w1vh] -> [comb_c|comb_s|-]
  const size_t oR2 = A(67108864);   // qrh|qrl (live through fine)
  const size_t oR4 = A(16777216);   // th|tl
  const size_t oR5 = A(16777216);   // v16->tv | vbh
  const size_t oR6 = A(16777216);   // kbh|kbl
  const size_t oR7 = A(16777216);   // krb|vT
  const size_t oR8 = A(3145728);    // g32
  const size_t oR9 = A(2097152);    // wch|wcl
  const size_t o_w2 = A(1572864);   // w2h|w2l|w2vh (written in prep kernel, own region)
  const size_t o_cos = A(524288),  o_sin = A(524288);
  const size_t o_ckh = A(163840),  o_ckl = A(163840);
  const size_t o_cvT = A(196608);
  const size_t o_woh = A(524288);
  const size_t o_imp = A(262144);
  const size_t o_part = A(8388608);   // stage-2 partials: k 4MB + v 4MB

  if (ws_size < off) {  // diagnostic: absmax will read ~ws_size in MiB
    nsa_sentinel<<<(out_size + 255)/256, 256, 0, stream>>>(out, out_size, (float)(ws_size >> 20));
    return;
  }

#define WP(T, o) ((T*)(ws + (o)))
  u16*  h_hi = WP(u16, oR1);           u16* h_lo = WP(u16, oR1 + 33554432);
  u16*  w1kh = WP(u16, oR1);           u16* w1kl = WP(u16, oR1 + 33554432);
  u16*  w1vh = WP(u16, oR1 + 67108864);
  u16*  combc = WP(u16, oR1);          // bf16 comb_c (32MB), after w1kh dead
  u16*  combs = WP(u16, oR1 + 33554432);  // bf16 comb_s (32MB), after w1kl dead
  u16*  qrh  = WP(u16, oR2);           u16* qrl  = WP(u16, oR2 + 33554432);
  u16*  th   = WP(u16, oR4);           u16* tl   = WP(u16, oR4 + 8388608);
  u16*  v16b = WP(u16, oR5);           u16* vbh  = WP(u16, oR5 + 8388608);
  u16*  tv   = WP(u16, oR5);           // alias: v16 dead after vT16
  u16*  kbh  = WP(u16, oR6);           u16* kbl  = WP(u16, oR6 + 8388608);
  u16*  krb  = WP(u16, oR7);           u16* vTb  = WP(u16, oR7 + 8388608);
  float* g32 = WP(float, oR8);
  u16*  wch  = WP(u16, oR9);           u16* wcl  = WP(u16, oR9 + 917504);
  u16*  w2h  = WP(u16, o_w2);          u16* w2l  = WP(u16, o_w2 + 524288);
  u16*  w2vh = WP(u16, o_w2 + 1048576);
  float* cosb = WP(float, o_cos);      float* sinb = WP(float, o_sin);
  u16*  ckh  = WP(u16, o_ckh);         u16* ckl  = WP(u16, o_ckl);
  u16*  cvT  = WP(u16, o_cvT);
  u16*  woh  = WP(u16, o_woh);
  float* imp = WP(float, o_imp);
  float* part = WP(float, o_part);

  nsa_hnorm<<<32768, 256, 0, stream>>>(x, pos, pe_w, pe_b, gamma, h_hi, h_lo);
  // merged prep: wcat + rope tables + w_out^T + w2^T (all input-only)
  nsa_wcat_rope<<<2496, 256, 0, stream>>>(wq, wk, wv, w_cmb, wch, wcl, cosb, sinb,
      w_out, woh, k_w2, w2h, w2l, v_w2, w2vh);
  // projection: single launch; q/k tiles split, v/gate tiles plain (runtime dsp)
  nsa_gemm<true, 0><<<dim3(256, 7, 1), 256, 0, stream>>>(h_hi, h_lo, wch, wcl, 512, 896,
      cosb, sinb, qrh, qrl, g32, k_pos, v_pos, krb, kbh, kbl, v16b, vbh);
  nsa_vT16<<<1024, 256, 0, stream>>>(v16b, vTb);
  // w1 transposes (k split, v plain); overwrite h after projection consumed it
  nsa_wT2<<<dim3(64, 64, 2), 256, 0, stream>>>(k_w1, w1kh, w1kl, v_w1, w1vh, nullptr, 4096, 4096);
  // merged MLP stage-1 (k split + v plain, fused bias+relu epilogue) [R12-best version]
  nsa_mlp1<<<512, 256, 0, stream>>>(kbh, kbl, vbh, w1kh, w1kl, w1vh, k_b1, v_b1, th, tl, tv);
  // merged stage-2 + reduction
  nsa_gemm64m<<<dim3(16, 32), 256, 0, stream>>>(th, tl, tv, w2h, w2l, w2vh, part);
  nsa_red_ckcv<<<704, 256, 0, stream>>>(part, mem_k, k_b2, mem_v, v_b2, ckh, ckl, cvT);
  // merged comp+slide (slide first), then fine (inline top2 + 3-way combine)
  nsa_attn_cs<<<1536, 256, 0, stream>>>(qrh, qrl, ckh, ckl, cvT, krb, vTb, g32, combc, combs, imp);
  nsa_attn_fine<<<1024, 256, 0, stream>>>(qrh, krb, vTb, imp, g32, combc, combs);
  // output projection (plain bf16, A = comb_c directly)
  nsa_gemm<false, 2><<<dim3(256, 4, 1), 256, 0, stream>>>(combc, nullptr, woh, nullptr, 512, 512,
      nullptr, out, nullptr, nullptr, nullptr, nullptr, nullptr, nullptr, nullptr, nullptr,
      nullptr, nullptr);
#undef WP
}

// Round 17
// 612.999 us; speedup vs baseline: 1.2483x; 1.0022x over previous
//
#include <hip/hip_runtime.h>
#include <stdint.h>

#define DEVI static __device__ __forceinline__
typedef unsigned short u16;
typedef __bf16 bhalf8 __attribute__((ext_vector_type(8)));
typedef float f32x4 __attribute__((ext_vector_type(4)));

DEVI u16 f2bf(float f) {
  union { float f; unsigned u; } v; v.f = f;
  unsigned r = v.u + 0x7FFFu + ((v.u >> 16) & 1u);
  return (u16)(r >> 16);
}
DEVI float bf2f(u16 h) {
  union { unsigned u; float f; } v; v.u = ((unsigned)h) << 16;
  return v.f;
}
DEVI f32x4 MFMA(bhalf8 a, bhalf8 b, f32x4 c) {
  return __builtin_amdgcn_mfma_f32_16x16x32_bf16(a, b, c, 0, 0, 0);
}
DEVI bhalf8 LD8(const u16* p) { return *(const bhalf8*)p; }
DEVI f32x4 zero4() { f32x4 z = {0.f, 0.f, 0.f, 0.f}; return z; }

// async global->LDS, 16B per lane, dest = wave-uniform base + lane*16
#define GLDS16(gp, lp) __builtin_amdgcn_global_load_lds( \
    (const __attribute__((address_space(1))) void*)(gp), \
    (__attribute__((address_space(3))) void*)(lp), 16, 0, 0)

// ================= prep / elementwise =================

__global__ __launch_bounds__(256) void nsa_hnorm(const float* __restrict__ x, const float* __restrict__ pos,
    const float* __restrict__ pew, const float* __restrict__ peb,
    const float* __restrict__ gamma, u16* __restrict__ hhi, u16* __restrict__ hlo) {
  int n = blockIdx.x, t = threadIdx.x;
  int blk = n >> 6;
  __shared__ float spm[3];
  if (t < 64) {
    const float* p = pos + (size_t)(blk * 64 + t) * 3;
    float a = p[0], b = p[1], c = p[2];
#pragma unroll
    for (int o = 32; o; o >>= 1) { a += __shfl_down(a, o); b += __shfl_down(b, o); c += __shfl_down(c, o); }
    if (t == 0) { spm[0] = a * (1.f/64.f); spm[1] = b * (1.f/64.f); spm[2] = c * (1.f/64.f); }
  }
  __syncthreads();
  float r0 = pos[(size_t)n*3+0] - spm[0];
  float r1 = pos[(size_t)n*3+1] - spm[1];
  float r2 = pos[(size_t)n*3+2] - spm[2];
  int c0 = t, c1 = t + 256;
  const float* xr = x + (size_t)n * 512;
  float v0 = xr[c0] + r0*pew[c0] + r1*pew[512+c0] + r2*pew[1024+c0] + peb[c0];
  float v1 = xr[c1] + r0*pew[c1] + r1*pew[512+c1] + r2*pew[1024+c1] + peb[c1];
  float ss = v0*v0 + v1*v1;
#pragma unroll
  for (int o = 32; o; o >>= 1) ss += __shfl_down(ss, o);
  __shared__ float red[4];
  if ((t & 63) == 0) red[t >> 6] = ss;
  __syncthreads();
  float rms = 1.0f / sqrtf((red[0]+red[1]+red[2]+red[3]) * (1.0f/512.0f) + 1e-6f);
  float h0 = v0 * rms * gamma[c0], h1 = v1 * rms * gamma[c1];
  u16 a0 = f2bf(h0); hhi[(size_t)n*512+c0] = a0; hlo[(size_t)n*512+c0] = f2bf(h0 - bf2f(a0));
  u16 a1 = f2bf(h1); hhi[(size_t)n*512+c1] = a1; hlo[(size_t)n*512+c1] = f2bf(h1 - bf2f(a1));
}

// merged prep: [0,1792) WcatT; [1792,2304) rope tables; [2304,2368) w_out^T;
// [2368,2432) k_w2^T (split); [2432,2496) v_w2^T. All input-only -> zero dependencies.
__global__ __launch_bounds__(256) void nsa_wcat_rope(const float* __restrict__ wq, const float* __restrict__ wk,
    const float* __restrict__ wv, const float* __restrict__ wc, u16* __restrict__ hi, u16* __restrict__ lo,
    float* __restrict__ ct, float* __restrict__ st,
    const float* __restrict__ wo, u16* __restrict__ woh,
    const float* __restrict__ kw2, u16* __restrict__ w2h, u16* __restrict__ w2l,
    const float* __restrict__ vw2, u16* __restrict__ w2vh) {
  int bidx = blockIdx.x;
  if (bidx < 1792) {
    int idx = bidx * 256 + threadIdx.x;  // 896*512
    int k = idx & 511, n = idx >> 9;
    float v;
    if (n < 512) v = wq[(size_t)k*512 + n];
    else if (n < 640) v = wk[(size_t)k*128 + n - 512];
    else if (n < 768) v = wv[(size_t)k*128 + n - 640];
    else if (n < 792) v = wc[(size_t)k*24 + n - 768];
    else v = 0.f;
    u16 h = f2bf(v); hi[idx] = h; lo[idx] = f2bf(v - bf2f(h));
  } else if (bidx < 2304) {
    int idx = (bidx - 1792) * 256 + threadIdx.x;  // 4096*32
    int s = idx >> 5, i = idx & 31;
    float e = (float)(2*i) * (1.0f/64.0f);
    float inv = 1.0f / powf(10000.0f, e);
    float f = (float)s * inv;
    ct[idx] = cosf(f); st[idx] = sinf(f);
  } else {
    __shared__ float tile[64][65];
    const float* src; u16* dhi; u16* dlo = nullptr; int K, N, k0, n0;
    if (bidx < 2368) {
      int j = bidx - 2304; src = wo; dhi = woh; K = 512; N = 512;
      k0 = (j & 7) * 64; n0 = (j >> 3) * 64;
    } else if (bidx < 2432) {
      int j = bidx - 2368; src = kw2; dhi = w2h; dlo = w2l; K = 4096; N = 64;
      k0 = j * 64; n0 = 0;
    } else {
      int j = bidx - 2432; src = vw2; dhi = w2vh; K = 4096; N = 64;
      k0 = j * 64; n0 = 0;
    }
    int t = threadIdx.x, r = t >> 2, c0 = (t & 3) * 16;
#pragma unroll
    for (int j = 0; j < 16; ++j) tile[r][c0+j] = src[(size_t)(k0+r)*N + n0 + c0 + j];
    __syncthreads();
    size_t ob = (size_t)(n0 + r)*K + k0 + c0;
    u16 bh[16], bl[16];
#pragma unroll
    for (int j = 0; j < 16; ++j) {
      float v = tile[c0+j][r];
      bh[j] = f2bf(v);
      bl[j] = f2bf(v - bf2f(bh[j]));
    }
    *(int4*)&dhi[ob] = *(int4*)&bh[0];
    *(int4*)&dhi[ob+8] = *(int4*)&bh[8];
    if (dlo) {
      *(int4*)&dlo[ob] = *(int4*)&bl[0];
      *(int4*)&dlo[ob+8] = *(int4*)&bl[8];
    }
  }
}

// v16 (B,KH,S,64 bf16) -> vT (B,KH,64,S bf16), packed int4 stores
__global__ __launch_bounds__(256) void nsa_vT16(const u16* __restrict__ v16, u16* __restrict__ vT) {
  int blk = blockIdx.x;  // (b*2+kh)*64 + chunk
  int st = (blk & 63) * 64, bkh = blk >> 6;
  __shared__ u16 tile[64][72];
  int t = threadIdx.x;
  int s = t >> 2, c0 = (t & 3) * 16;
  const u16* src = v16 + ((size_t)bkh*4096 + st + s) * 64;
  *(int4*)&tile[s][c0]   = *(const int4*)&src[c0];
  *(int4*)&tile[s][c0+8] = *(const int4*)&src[c0+8];
  __syncthreads();
  int d = t >> 2, s0 = (t & 3) * 16;
  u16* dst = vT + ((size_t)bkh*64 + d)*4096 + st + s0;
  u16 buf[16];
#pragma unroll
  for (int j = 0; j < 16; ++j) buf[j] = tile[s0+j][d];
  *(int4*)&dst[0] = *(int4*)&buf[0];
  *(int4*)&dst[8] = *(int4*)&buf[8];
}

// dual transpose via z: z=0 -> (srcA, dhA, dlA), z=1 -> (srcB, dhB, dlB); packed int4 stores
__global__ __launch_bounds__(256) void nsa_wT2(const float* __restrict__ srcA, u16* __restrict__ dhA,
    u16* __restrict__ dlA, const float* __restrict__ srcB, u16* __restrict__ dhB, u16* __restrict__ dlB,
    int K, int N) {
  const float* src = blockIdx.z ? srcB : srcA;
  u16* dhi = blockIdx.z ? dhB : dhA;
  u16* dlo = blockIdx.z ? dlB : dlA;
  __shared__ float tile[64][65];
  int k0 = blockIdx.x * 64, n0 = blockIdx.y * 64;
  int t = threadIdx.x, r = t >> 2, c0 = (t & 3) * 16;
#pragma unroll
  for (int j = 0; j < 16; ++j) tile[r][c0+j] = src[(size_t)(k0+r)*N + n0 + c0 + j];
  __syncthreads();
  size_t ob = (size_t)(n0 + r)*K + k0 + c0;
  u16 bh[16], bl[16];
#pragma unroll
  for (int j = 0; j < 16; ++j) {
    float v = tile[c0+j][r];
    bh[j] = f2bf(v);
    bl[j] = f2bf(v - bf2f(bh[j]));
  }
  *(int4*)&dhi[ob] = *(int4*)&bh[0];
  *(int4*)&dhi[ob+8] = *(int4*)&bh[8];
  if (dlo) {
    *(int4*)&dlo[ob] = *(int4*)&bl[0];
    *(int4*)&dlo[ob+8] = *(int4*)&bl[8];
  }
}

// merged reduce of stage-2 partials: idx<81920 -> ck hi/lo (B,KH,80,64); else cvT (B,KH,64,96)
__global__ __launch_bounds__(256) void nsa_red_ckcv(const float* __restrict__ part,
    const float* __restrict__ mem_k, const float* __restrict__ kb2,
    const float* __restrict__ mem_v, const float* __restrict__ vb2,
    u16* __restrict__ ckh, u16* __restrict__ ckl, u16* __restrict__ cvT) {
  int idx = blockIdx.x * 256 + threadIdx.x;
  if (idx < 81920) {
    int d = idx & 63, n = (idx >> 6) % 80, bkh = idx / (80*64);
    int kh = bkh & 1;
    float v;
    if (n == 0) v = mem_k[kh*64 + d];
    else if (n <= 64) {
      v = kb2[d];
      int m = bkh*64 + (n - 1);
#pragma unroll
      for (int kc = 0; kc < 16; ++kc) v += part[((size_t)kc*1024 + m)*64 + d];
    } else v = 0.f;
    u16 h = f2bf(v); ckh[idx] = h; ckl[idx] = f2bf(v - bf2f(h));
  } else if (idx < 81920 + 98304) {
    int j = idx - 81920;
    int cc = j % 96, d = (j / 96) & 63, bkh = j / (96*64);
    int kh = bkh & 1;
    const float* pv = part + (size_t)16*1024*64;
    float v;
    if (cc == 0) v = mem_v[kh*64 + d];
    else if (cc <= 64) {
      v = vb2[d];
      int m = bkh*64 + (cc - 1);
#pragma unroll
      for (int kc = 0; kc < 16; ++kc) v += pv[((size_t)kc*1024 + m)*64 + d];
    } else v = 0.f;
    cvT[j] = f2bf(v);
  }
}

__global__ __launch_bounds__(256) void nsa_sentinel(float* __restrict__ o, int n, float val) {
  int i = blockIdx.x * 256 + threadIdx.x;
  if (i < n) o[i] = val;
}

// ================= GEMMs =================
// C = A @ B^T. 2-phase dbuf LDS, global_load_lds w16, both-sides XOR swizzle.
// EPI 0 (projection, single launch grid(256,7)): runtime dsp = (n0 <= 512); A-reuse swizzle.
// EPI 2: plain f32 out (p_sin = out), generic XCD swizzle.
template<bool SPLIT, int EPI>
__global__ __launch_bounds__(256) void nsa_gemm(const u16* __restrict__ Ah, const u16* __restrict__ Al,
    const u16* __restrict__ Bh, const u16* __restrict__ Bl, int K, int N,
    const float* __restrict__ p_cos, float* __restrict__ p_sin,
    u16* __restrict__ out_hi, u16* __restrict__ out_lo, float* __restrict__ og,
    const float* __restrict__ kpos, const float* __restrict__ vpos,
    u16* __restrict__ krb, u16* __restrict__ kbh, u16* __restrict__ kbl,
    u16* __restrict__ v16o, u16* __restrict__ vbh) {
  constexpr int NB = SPLIT ? 4 : 2;
  __shared__ u16 sm[NB * 2 * 4096];
  const int t = threadIdx.x, w = t >> 6, l = t & 63;
  const int wm = w >> 1, wn = w & 1;
  int m0, n0;
  if constexpr (EPI == 0) {
    const int nper = (int)gridDim.y;
    const int bid = blockIdx.y * 256 + blockIdx.x;
    const int xcd = bid & 7, j = bid >> 3;
    const int mg = j / (8*nper), rem = j % (8*nper);
    const int nn = rem >> 3, mi = rem & 7;
    m0 = ((xcd * 4 + mg) * 8 + mi) * 128;
    n0 = nn * 128;
  } else {
    const int MBn = gridDim.x;
    const int nwg = MBn * gridDim.y;
    const int bid = blockIdx.y * MBn + blockIdx.x;
    const int swz = (bid & 7) * (nwg >> 3) + (bid >> 3);
    m0 = (swz % MBn) * 128; n0 = (swz / MBn) * 128;
  }
  const bool dsp = SPLIT && (EPI != 0 || n0 <= 512);  // runtime precision per block
  const int row = l & 15;
  const int kc8 = ((l >> 4) ^ ((l >> 1) & 3)) * 8;
  const int gsc = ((l & 3) ^ ((l >> 3) & 3)) * 8;
  const int sr = l >> 2;
  f32x4 acc[4][4];
#pragma unroll
  for (int a = 0; a < 4; ++a)
#pragma unroll
    for (int b = 0; b < 4; ++b) acc[a][b] = zero4();

  auto STAGE = [&](int buf, int k0) {
    u16* base = sm + buf * NB * 4096;
#pragma unroll
    for (int s2 = 0; s2 < 2; ++s2) {
      int seg = w*2 + s2;
      int r = seg*16 + sr;
      size_t ga = (size_t)(m0 + r)*K + k0 + gsc;
      size_t gb = (size_t)(n0 + r)*K + k0 + gsc;
      GLDS16(&Ah[ga], base + seg*512);
      GLDS16(&Bh[gb], base + 4096 + seg*512);
      if (SPLIT && dsp) {
        GLDS16(&Al[ga], base + 2*4096 + seg*512);
        GLDS16(&Bl[gb], base + 3*4096 + seg*512);
      }
    }
  };

  const int nt = K >> 5;
  STAGE(0, 0);
  __syncthreads();
  int cur = 0;
  for (int kt = 0; kt < nt; ++kt) {
    if (kt + 1 < nt) STAGE(cur ^ 1, (kt + 1) * 32);
    u16* bA  = sm + cur * NB * 4096;
    u16* bB  = bA + 4096;
    u16* bAl = bA + 2*4096;
    u16* bBl = bA + 3*4096;
    bhalf8 af[4], afl[4];
#pragma unroll
    for (int mf = 0; mf < 4; ++mf) {
      af[mf] = LD8(&bA[(wm*64 + mf*16 + row)*32 + kc8]);
      if (dsp) afl[mf] = LD8(&bAl[(wm*64 + mf*16 + row)*32 + kc8]);
    }
#pragma unroll
    for (int nf = 0; nf < 4; ++nf) {
      bhalf8 bfh = LD8(&bB[(wn*64 + nf*16 + row)*32 + kc8]);
      bhalf8 bfl;
      if (dsp) bfl = LD8(&bBl[(wn*64 + nf*16 + row)*32 + kc8]);
#pragma unroll
      for (int mf = 0; mf < 4; ++mf) {
        acc[mf][nf] = MFMA(af[mf], bfh, acc[mf][nf]);
        if (dsp) {
          acc[mf][nf] = MFMA(af[mf], bfl, acc[mf][nf]);
          acc[mf][nf] = MFMA(afl[mf], bfh, acc[mf][nf]);
        }
      }
    }
    __syncthreads();
    cur ^= 1;
  }
  if constexpr (EPI == 0) {
    if (n0 < 512) {
      // q columns: fused GPT-NeoX rotary. cols c (dd<32) pair with c+32 = acc[mf][nf+2].
#pragma unroll
      for (int mf = 0; mf < 4; ++mf)
#pragma unroll
        for (int i = 0; i < 4; ++i) {
          int r = m0 + wm*64 + mf*16 + (l >> 4)*4 + i;
          int s = r & 4095, b = r >> 12;
#pragma unroll
          for (int nf = 0; nf < 2; ++nf) {
            int c = n0 + wn*64 + nf*16 + (l & 15);
            int hq = c >> 6, dd = c & 31;
            float t1 = acc[mf][nf][i], t2 = acc[mf][nf+2][i];
            float cs = p_cos[s*32 + dd], sn = p_sin[s*32 + dd];
            float o1 = t1*cs - t2*sn, o2 = t2*cs + t1*sn;
            size_t ob = (((size_t)(b*8 + hq))*4096 + s)*64;
            u16 h1 = f2bf(o1); out_hi[ob+dd] = h1;    out_lo[ob+dd] = f2bf(o1 - bf2f(h1));
            u16 h2 = f2bf(o2); out_hi[ob+dd+32] = h2; out_lo[ob+dd+32] = f2bf(o2 - bf2f(h2));
          }
        }
    } else if (n0 == 512) {
      // k columns: fused rotary -> krb; (k + k_pos) split -> kbh/kbl
      int kh = wn;
#pragma unroll
      for (int mf = 0; mf < 4; ++mf)
#pragma unroll
        for (int i = 0; i < 4; ++i) {
          int r = m0 + wm*64 + mf*16 + (l >> 4)*4 + i;
          int s = r & 4095, b = r >> 12;
          int n = s >> 6, sl = s & 63;
          size_t krbase = ((size_t)(b*2 + kh)*4096 + s)*64;
          size_t kbbase = ((size_t)(b*128 + kh*64 + n))*4096 + sl*64;
#pragma unroll
          for (int nf = 0; nf < 2; ++nf) {
            int dd = nf*16 + (l & 15);
            float t1 = acc[mf][nf][i], t2 = acc[mf][nf+2][i];
            float cs = p_cos[s*32 + dd], sn = p_sin[s*32 + dd];
            krb[krbase + dd]      = f2bf(t1*cs - t2*sn);
            krb[krbase + dd + 32] = f2bf(t2*cs + t1*sn);
          }
#pragma unroll
          for (int nf = 0; nf < 4; ++nf) {
            int dk = nf*16 + (l & 15);
            float v = acc[mf][nf][i] + kpos[(kh*64 + sl)*64 + dk];
            u16 h = f2bf(v);
            kbh[kbbase + dk] = h;
            kbl[kbbase + dk] = f2bf(v - bf2f(h));
          }
        }
    } else if (n0 == 640) {
      // v columns: v16 bf16 + (v + v_pos) -> vbh (plain)
      int kh = wn;
#pragma unroll
      for (int mf = 0; mf < 4; ++mf)
#pragma unroll
        for (int i = 0; i < 4; ++i) {
          int r = m0 + wm*64 + mf*16 + (l >> 4)*4 + i;
          int s = r & 4095, b = r >> 12;
          int n = s >> 6, sl = s & 63;
          size_t v16base = ((size_t)(b*2 + kh)*4096 + s)*64;
          size_t vbbase = ((size_t)(b*128 + kh*64 + n))*4096 + sl*64;
#pragma unroll
          for (int nf = 0; nf < 4; ++nf) {
            int dv = nf*16 + (l & 15);
            float vv = acc[mf][nf][i];
            v16o[v16base + dv] = f2bf(vv);
            vbh[vbbase + dv] = f2bf(vv + vpos[(kh*64 + sl)*64 + dv]);
          }
        }
    } else {
#pragma unroll
      for (int mf = 0; mf < 4; ++mf)
#pragma unroll
        for (int nf = 0; nf < 4; ++nf)
#pragma unroll
          for (int i = 0; i < 4; ++i) {
            int r = m0 + wm*64 + mf*16 + (l >> 4)*4 + i;
            int c = n0 + wn*64 + nf*16 + (l & 15);
            if (c < 792) og[(size_t)r*24 + (c - 768)] = 1.0f / (1.0f + expf(-acc[mf][nf][i]));
          }
    }
  } else {  // EPI == 2
#pragma unroll
    for (int mf = 0; mf < 4; ++mf)
#pragma unroll
      for (int nf = 0; nf < 4; ++nf)
#pragma unroll
        for (int i = 0; i < 4; ++i) {
          int r = m0 + wm*64 + mf*16 + (l >> 4)*4 + i;
          int c = n0 + wn*64 + nf*16 + (l & 15);
          p_sin[(size_t)r*N + c] = acc[mf][nf][i];
        }
  }
}

// merged MLP stage-1 (R12-measured-best): grid 512. Block u<32 -> k (split, 3 MFMA, out th/tl);
// u>=32 -> v (plain, out tv). Per-XCD: 4 k-coltiles + 4 v-coltiles, m-minor. Fused bias+relu.
__global__ __launch_bounds__(256) void nsa_mlp1(const u16* __restrict__ kbh, const u16* __restrict__ kbl,
    const u16* __restrict__ vbh, const u16* __restrict__ w1kh, const u16* __restrict__ w1kl,
    const u16* __restrict__ w1vh, const float* __restrict__ kb1, const float* __restrict__ vb1,
    u16* __restrict__ th, u16* __restrict__ tl, u16* __restrict__ tv) {
  __shared__ u16 sm[4 * 2 * 4096];  // 64KB
  const int t = threadIdx.x, w = t >> 6, l = t & 63;
  const int wm = w >> 1, wn = w & 1;
  const int bid = blockIdx.x;
  const int xcd = bid & 7, u = bid >> 3;
  const bool isK = u < 32;
  const int uu = isK ? u : u - 32;
  const int m0 = (uu & 7) * 128;
  const int n0 = (xcd * 4 + (uu >> 3)) * 128;
  const u16* Ah = isK ? kbh : vbh;
  const u16* Bh = isK ? w1kh : w1vh;
  constexpr int K = 4096;
  const int row = l & 15;
  const int kc8 = ((l >> 4) ^ ((l >> 1) & 3)) * 8;
  const int gsc = ((l & 3) ^ ((l >> 3) & 3)) * 8;
  const int sr = l >> 2;
  f32x4 acc[4][4];
#pragma unroll
  for (int a = 0; a < 4; ++a)
#pragma unroll
    for (int b = 0; b < 4; ++b) acc[a][b] = zero4();

  auto STAGE = [&](int buf, int k0) {
    u16* base = sm + buf * 4 * 4096;
#pragma unroll
    for (int s2 = 0; s2 < 2; ++s2) {
      int seg = w*2 + s2;
      int r = seg*16 + sr;
      size_t ga = (size_t)(m0 + r)*K + k0 + gsc;
      size_t gb = (size_t)(n0 + r)*K + k0 + gsc;
      GLDS16(&Ah[ga], base + seg*512);
      GLDS16(&Bh[gb], base + 4096 + seg*512);
      if (isK) {
        GLDS16(&kbl[ga], base + 2*4096 + seg*512);
        GLDS16(&w1kl[gb], base + 3*4096 + seg*512);
      }
    }
  };

  STAGE(0, 0);
  __syncthreads();
  int cur = 0;
  for (int kt = 0; kt < 128; ++kt) {
    if (kt + 1 < 128) STAGE(cur ^ 1, (kt + 1) * 32);
    u16* bA  = sm + cur * 4 * 4096;
    u16* bB  = bA + 4096;
    u16* bAl = bA + 2*4096;
    u16* bBl = bA + 3*4096;
    bhalf8 af[4], afl[4];
#pragma unroll
    for (int mf = 0; mf < 4; ++mf) {
      af[mf] = LD8(&bA[(wm*64 + mf*16 + row)*32 + kc8]);
      if (isK) afl[mf] = LD8(&bAl[(wm*64 + mf*16 + row)*32 + kc8]);
    }
#pragma unroll
    for (int nf = 0; nf < 4; ++nf) {
      bhalf8 bfh = LD8(&bB[(wn*64 + nf*16 + row)*32 + kc8]);
      bhalf8 bfl;
      if (isK) bfl = LD8(&bBl[(wn*64 + nf*16 + row)*32 + kc8]);
#pragma unroll
      for (int mf = 0; mf < 4; ++mf) {
        acc[mf][nf] = MFMA(af[mf], bfh, acc[mf][nf]);
        if (isK) {
          acc[mf][nf] = MFMA(af[mf], bfl, acc[mf][nf]);
          acc[mf][nf] = MFMA(afl[mf], bfh, acc[mf][nf]);
        }
      }
    }
    __syncthreads();
    cur ^= 1;
  }
  const float* bias = isK ? kb1 : vb1;
#pragma unroll
  for (int mf = 0; mf < 4; ++mf)
#pragma unroll
    for (int nf = 0; nf < 4; ++nf)
#pragma unroll
      for (int i = 0; i < 4; ++i) {
        int r = m0 + wm*64 + mf*16 + (l >> 4)*4 + i;
        int c = n0 + wn*64 + nf*16 + (l & 15);
        float v = fmaxf(acc[mf][nf][i] + bias[c], 0.f);
        if (isK) {
          u16 h = f2bf(v);
          th[(size_t)r*4096 + c] = h;
          tl[(size_t)r*4096 + c] = f2bf(v - bf2f(h));
        } else {
          tv[(size_t)r*4096 + c] = f2bf(v);
        }
      }
}

// merged stage-2: grid (16,32). y<16 -> k (split, A=th/tl, B=w2h/w2l); y>=16 -> v (plain).
// 16 K-slices of 256 each -> deterministic partials.
__global__ __launch_bounds__(256) void nsa_gemm64m(const u16* __restrict__ th, const u16* __restrict__ tl,
    const u16* __restrict__ tv, const u16* __restrict__ w2h, const u16* __restrict__ w2l,
    const u16* __restrict__ w2vh, float* __restrict__ part) {
  __shared__ u16 sm[4 * 2 * 2048];  // 32KB
  const int t = threadIdx.x, w = t >> 6, l = t & 63;
  const int mt = blockIdx.x;
  const bool isK = blockIdx.y < 16;
  const int kc = blockIdx.y & 15;
  const u16* Ah = isK ? th : tv;
  const u16* Bh = isK ? w2h : w2vh;
  float* po = part + (isK ? 0 : (size_t)16*1024*64);
  const int row = l & 15;
  const int kc8 = ((l >> 4) ^ ((l >> 1) & 3)) * 8;
  const int gsc = ((l & 3) ^ ((l >> 3) & 3)) * 8;
  const int sr = l >> 2;
  f32x4 acc[4];
#pragma unroll
  for (int a = 0; a < 4; ++a) acc[a] = zero4();

  auto STAGE = [&](int buf, int k0) {
    u16* base = sm + buf * 4 * 2048;
    int r = w*16 + sr;
    size_t ga = (size_t)(mt*64 + r)*4096 + k0 + gsc;
    size_t gb = (size_t)r*4096 + k0 + gsc;
    GLDS16(&Ah[ga], base + w*512);
    GLDS16(&Bh[gb], base + 2048 + w*512);
    if (isK) {
      GLDS16(&tl[ga], base + 2*2048 + w*512);
      GLDS16(&w2l[gb], base + 3*2048 + w*512);
    }
  };

  STAGE(0, kc*256);
  __syncthreads();
  int cur = 0;
  for (int kt = 0; kt < 8; ++kt) {
    if (kt + 1 < 8) STAGE(cur ^ 1, kc*256 + (kt + 1) * 32);
    u16* bA  = sm + cur * 4 * 2048;
    u16* bB  = bA + 2048;
    u16* bAl = bA + 2*2048;
    u16* bBl = bA + 3*2048;
    bhalf8 a = LD8(&bA[(w*16 + row)*32 + kc8]);
    bhalf8 al;
    if (isK) al = LD8(&bAl[(w*16 + row)*32 + kc8]);
#pragma unroll
    for (int nf = 0; nf < 4; ++nf) {
      bhalf8 b = LD8(&bB[(nf*16 + row)*32 + kc8]);
      bhalf8 bl;
      if (isK) bl = LD8(&bBl[(nf*16 + row)*32 + kc8]);
      acc[nf] = MFMA(a, b, acc[nf]);
      if (isK) {
        acc[nf] = MFMA(a, bl, acc[nf]);
        acc[nf] = MFMA(al, b, acc[nf]);
      }
    }
    __syncthreads();
    cur ^= 1;
  }
#pragma unroll
  for (int nf = 0; nf < 4; ++nf)
#pragma unroll
    for (int i = 0; i < 4; ++i) {
      int m = mt*64 + w*16 + (l >> 4)*4 + i;
      int d = nf*16 + (l & 15);
      po[((size_t)kc*1024 + m)*64 + d] = acc[nf][i];
    }
}

// ================= attention =================

// merged comp+slide: blocks [0,512) = slide (writes comb_s); [512,1536) = comp (writes comb_c + imp).
__global__ __launch_bounds__(256) void nsa_attn_cs(const u16* __restrict__ qrh, const u16* __restrict__ qrl,
    const u16* __restrict__ ckh, const u16* __restrict__ ckl, const u16* __restrict__ cvT,
    const u16* __restrict__ kr, const u16* __restrict__ vT, const float* __restrict__ g32,
    u16* __restrict__ comb_c, u16* __restrict__ comb_s, float* __restrict__ imp) {
  __shared__ u16 smem[26624];
  __shared__ float sImp[4 * 80];
  const int t = threadIdx.x, w = t >> 6, l = t & 63;
  const int row = l & 15, kg = (l >> 4) * 8;
  if (blockIdx.x < 512) {
    // ---------- sliding path ----------
    u16* sK  = smem;            // 128*72 = 9216
    u16* sVT = smem + 9216;     // 64*136 = 8704
    u16* sP  = smem + 17920;    // 64*136 = 8704
    const int bid = blockIdx.x;
    const int ball = bid & 31, kh = (bid >> 5) & 1, b = bid >> 6;
    const int ks0 = ball * 128;
    size_t kvb = (size_t)(b*2 + kh) * 4096 * 64;
    size_t vtb = (size_t)(b*2 + kh) * 64 * 4096;
    for (int e = t; e < 1024; e += 256) {
      int r = e >> 3, c = (e & 7) * 8;
      *(int4*)&sK[r*72 + c] = *(const int4*)&kr[kvb + (size_t)(ks0 + r)*64 + c];
    }
    for (int e = t; e < 1024; e += 256) {
      int r = e >> 4, ch = e & 15;
      *(int4*)&sVT[r*136 + ch*8] = *(const int4*)&vT[vtb + (size_t)r*4096 + ks0 + ch*8];
    }
    __syncthreads();
    for (int hq = 0; hq < 4; ++hq) {
      int hh = kh*4 + hq;
      for (int qh = 0; qh < 2; ++qh) {
        int qt = ball*2 + qh;
        size_t qbase = ((size_t)(b*8 + hh)*4096 + qt*64) * 64 + (size_t)(w*16 + row)*64;
        bhalf8 a0 = LD8(&qrh[qbase + kg]);
        bhalf8 a1 = LD8(&qrh[qbase + 32 + kg]);
        f32x4 sc[8];
#pragma unroll
        for (int nf = 0; nf < 8; ++nf) sc[nf] = zero4();
#pragma unroll
        for (int kk = 0; kk < 2; ++kk) {
          bhalf8 a = kk ? a1 : a0;
#pragma unroll
          for (int nf = 0; nf < 8; ++nf) {
            bhalf8 bk = LD8(&sK[(nf*16 + row)*72 + kk*32 + kg]);
            sc[nf] = MFMA(a, bk, sc[nf]);
          }
        }
        float mx[4] = {-1e30f, -1e30f, -1e30f, -1e30f};
#pragma unroll
        for (int nf = 0; nf < 8; ++nf)
#pragma unroll
          for (int i = 0; i < 4; ++i) {
            float v = sc[nf][i] * 0.125f;
            sc[nf][i] = v;
            mx[i] = fmaxf(mx[i], v);
          }
#pragma unroll
        for (int i = 0; i < 4; ++i)
#pragma unroll
          for (int o = 1; o < 16; o <<= 1) mx[i] = fmaxf(mx[i], __shfl_xor(mx[i], o));
        float sum[4] = {0.f, 0.f, 0.f, 0.f};
#pragma unroll
        for (int nf = 0; nf < 8; ++nf)
#pragma unroll
          for (int i = 0; i < 4; ++i) {
            float p = expf(sc[nf][i] - mx[i]);
            sc[nf][i] = p;
            sum[i] += p;
          }
#pragma unroll
        for (int i = 0; i < 4; ++i)
#pragma unroll
          for (int o = 1; o < 16; o <<= 1) sum[i] += __shfl_xor(sum[i], o);
        float inv[4];
#pragma unroll
        for (int i = 0; i < 4; ++i) inv[i] = 1.0f / sum[i];
#pragma unroll
        for (int nf = 0; nf < 8; ++nf)
#pragma unroll
          for (int i = 0; i < 4; ++i)
            sP[(w*16 + (l >> 4)*4 + i)*136 + nf*16 + (l & 15)] = f2bf(sc[nf][i] * inv[i]);
        f32x4 ovv[4];
#pragma unroll
        for (int nf = 0; nf < 4; ++nf) ovv[nf] = zero4();
#pragma unroll
        for (int kk = 0; kk < 4; ++kk) {
          bhalf8 a = LD8(&sP[(w*16 + row)*136 + kk*32 + kg]);
#pragma unroll
          for (int nf = 0; nf < 4; ++nf) {
            bhalf8 bv = LD8(&sVT[(nf*16 + row)*136 + kk*32 + kg]);
            ovv[nf] = MFMA(a, bv, ovv[nf]);
          }
        }
#pragma unroll
        for (int i = 0; i < 4; ++i) {
          int q = qt*64 + w*16 + (l >> 4)*4 + i;
          float gate = g32[((size_t)b*4096 + q)*24 + hh*3 + 2];
#pragma unroll
          for (int nf = 0; nf < 4; ++nf) {
            int d = nf*16 + (l & 15);
            size_t oi = (((size_t)b*4096 + q)*8 + hh)*64 + d;
            comb_s[oi] = f2bf(gate * ovv[nf][i]);
          }
        }
      }
    }
  } else {
    // ---------- compressed path ----------
    u16* sKh = smem;            // 80*72 = 5760
    u16* sKl = smem + 5760;     // 5760
    u16* sVT = smem + 11520;    // 64*104 = 6656
    u16* sP  = smem + 18176;    // 64*104 = 6656
    const int bid = blockIdx.x - 512;  // 0..1023
    const int qt = bid & 63, kh = (bid >> 6) & 1, b = bid >> 7;
    size_t kbase = (size_t)(b*2 + kh) * 80 * 64;
    size_t vbase = (size_t)(b*2 + kh) * 64 * 96;
    for (int e = t; e < 640; e += 256) {
      int r = e >> 3, c = (e & 7) * 8;
      *(int4*)&sKh[r*72 + c] = *(const int4*)&ckh[kbase + r*64 + c];
      *(int4*)&sKl[r*72 + c] = *(const int4*)&ckl[kbase + r*64 + c];
    }
    for (int e = t; e < 768; e += 256) {
      int r = e / 12, ch = e % 12;
      *(int4*)&sVT[r*104 + ch*8] = *(const int4*)&cvT[vbase + (size_t)r*96 + ch*8];
    }
    for (int e = l; e < 80; e += 64) sImp[w*80 + e] = 0.f;
#pragma unroll
    for (int i = 0; i < 4; ++i)
      sP[(w*16 + (l & 15))*104 + 80 + (l >> 4)*4 + i] = 0;
    __syncthreads();
    for (int g = 0; g < 4; ++g) {
      size_t qbase = ((size_t)((b*2 + kh)*4 + g)*4096 + qt*64) * 64 + (size_t)(w*16 + row)*64;
      bhalf8 ah0 = LD8(&qrh[qbase + kg]);
      bhalf8 ah1 = LD8(&qrh[qbase + 32 + kg]);
      bhalf8 al0 = LD8(&qrl[qbase + kg]);
      bhalf8 al1 = LD8(&qrl[qbase + 32 + kg]);
      f32x4 sc[5];
#pragma unroll
      for (int nf = 0; nf < 5; ++nf) sc[nf] = zero4();
#pragma unroll
      for (int kk = 0; kk < 2; ++kk) {
        bhalf8 ah = kk ? ah1 : ah0;
        bhalf8 al = kk ? al1 : al0;
#pragma unroll
        for (int nf = 0; nf < 5; ++nf) {
          bhalf8 bh = LD8(&sKh[(nf*16 + row)*72 + kk*32 + kg]);
          bhalf8 bl = LD8(&sKl[(nf*16 + row)*72 + kk*32 + kg]);
          sc[nf] = MFMA(ah, bh, sc[nf]);
          sc[nf] = MFMA(ah, bl, sc[nf]);
          sc[nf] = MFMA(al, bh, sc[nf]);
        }
      }
      float mx[4] = {-1e30f, -1e30f, -1e30f, -1e30f};
#pragma unroll
      for (int nf = 0; nf < 5; ++nf)
#pragma unroll
        for (int i = 0; i < 4; ++i) {
          int col = nf*16 + (l & 15);
          float v = (col < 65) ? sc[nf][i] * 0.125f : -1e30f;
          sc[nf][i] = v;
          mx[i] = fmaxf(mx[i], v);
        }
#pragma unroll
      for (int i = 0; i < 4; ++i)
#pragma unroll
        for (int o = 1; o < 16; o <<= 1) mx[i] = fmaxf(mx[i], __shfl_xor(mx[i], o));
      float sum[4] = {0.f, 0.f, 0.f, 0.f};
#pragma unroll
      for (int nf = 0; nf < 5; ++nf)
#pragma unroll
        for (int i = 0; i < 4; ++i) {
          int col = nf*16 + (l & 15);
          float p = (col < 65) ? expf(sc[nf][i] - mx[i]) : 0.f;
          sc[nf][i] = p;
          sum[i] += p;
        }
#pragma unroll
      for (int i = 0; i < 4; ++i)
#pragma unroll
        for (int o = 1; o < 16; o <<= 1) sum[i] += __shfl_xor(sum[i], o);
      float inv[4];
#pragma unroll
      for (int i = 0; i < 4; ++i) inv[i] = 1.0f / sum[i];
#pragma unroll
      for (int nf = 0; nf < 5; ++nf)
#pragma unroll
        for (int i = 0; i < 4; ++i)
          sP[(w*16 + (l >> 4)*4 + i)*104 + nf*16 + (l & 15)] = f2bf(sc[nf][i] * inv[i]);
#pragma unroll
      for (int nf = 0; nf < 5; ++nf) {
        float cs = 0.f;
#pragma unroll
        for (int i = 0; i < 4; ++i) cs += sc[nf][i] * inv[i];
        cs += __shfl_xor(cs, 16);
        cs += __shfl_xor(cs, 32);
        if (l < 16) sImp[w*80 + nf*16 + l] += cs;
      }
      f32x4 ov[4];
#pragma unroll
      for (int nf = 0; nf < 4; ++nf) ov[nf] = zero4();
#pragma unroll
      for (int kk = 0; kk < 3; ++kk) {
        bhalf8 a = LD8(&sP[(w*16 + row)*104 + kk*32 + kg]);
#pragma unroll
        for (int nf = 0; nf < 4; ++nf) {
          bhalf8 bv = LD8(&sVT[(nf*16 + row)*104 + kk*32 + kg]);
          ov[nf] = MFMA(a, bv, ov[nf]);
        }
      }
      int hq = kh*4 + g;
#pragma unroll
      for (int i = 0; i < 4; ++i) {
        int q = qt*64 + w*16 + (l >> 4)*4 + i;
        float gate = g32[((size_t)b*4096 + q)*24 + hq*3 + 0];
#pragma unroll
        for (int nf = 0; nf < 4; ++nf) {
          int d = nf*16 + (l & 15);
          comb_c[(((size_t)b*4096 + q)*8 + hq)*64 + d] = f2bf(gate * ov[nf][i]);
        }
      }
    }
    __syncthreads();
    if (t < 64) {
      int n = t + 1;
      imp[(size_t)bid*64 + t] = (sImp[n] + sImp[80 + n] + sImp[160 + n] + sImp[240 + n]) * (1.0f/256.0f);
    }
  }
}

// fine: per (b,kh,qblk): inline top-2 (wave 0 from imp); K/VT staged ONCE; Q fragments from
// global; sP wave-private; barrier-free g loop. Final combine: comb_c += comb_s + gate*fine.
__global__ __launch_bounds__(256) void nsa_attn_fine(const u16* __restrict__ qrh, const u16* __restrict__ kr,
    const u16* __restrict__ vT, const float* __restrict__ imp, const float* __restrict__ g32,
    u16* __restrict__ comb_c, const u16* __restrict__ comb_s) {
  __shared__ u16 smem[39424];
  __shared__ int ssel[2];
  u16* sK  = smem;            // 192*72 = 13824
  u16* sVT = smem + 13824;    // 64*200 = 12800
  u16* sP  = smem + 26624;    // 64*200 = 12800
  const int t = threadIdx.x, w = t >> 6, l = t & 63;
  const int bid = blockIdx.x;
  const int qt = bid & 63, kh = (bid >> 6) & 1, b = bid >> 7;
  const int row = l & 15, kg = (l >> 4) * 8;
  if (t < 64) {  // inline top-2 over this block's 64 importance values
    float v = imp[(size_t)bid*64 + t];
    float v1 = v; int i1 = t;
#pragma unroll
    for (int o = 1; o < 64; o <<= 1) {
      float ovv = __shfl_xor(v1, o); int oi = __shfl_xor(i1, o);
      if (ovv > v1 || (ovv == v1 && oi < i1)) { v1 = ovv; i1 = oi; }
    }
    float v2 = (t == i1) ? -3.0e38f : v; int i2 = t;
#pragma unroll
    for (int o = 1; o < 64; o <<= 1) {
      float ovv = __shfl_xor(v2, o); int oi = __shfl_xor(i2, o);
      if (ovv > v2 || (ovv == v2 && oi < i2)) { v2 = ovv; i2 = oi; }
    }
    if (t == 0) { ssel[0] = i1; ssel[1] = i2; }
  }
  __syncthreads();
  const int s0 = ssel[0] & 63, s1 = ssel[1] & 63;
  size_t kvb = (size_t)(b*2 + kh) * 4096 * 64;
  size_t vtb = (size_t)(b*2 + kh) * 64 * 4096;
  for (int e = t; e < 1536; e += 256) {
    int r = e >> 3, c = (e & 7) * 8;
    int bi = r >> 6;
    int blkid = (bi == 0) ? s0 : ((bi == 1) ? s1 : qt);
    int sidx = blkid*64 + (r & 63);
    *(int4*)&sK[r*72 + c] = *(const int4*)&kr[kvb + (size_t)sidx*64 + c];
  }
  for (int e = t; e < 1536; e += 256) {
    int r = e / 24, ch = e % 24;
    int n0 = ch * 8, bi = n0 >> 6;
    int blkid = (bi == 0) ? s0 : ((bi == 1) ? s1 : qt);
    int sidx = blkid*64 + (n0 & 63);
    *(int4*)&sVT[r*200 + n0] = *(const int4*)&vT[vtb + (size_t)r*4096 + sidx];
  }
  __syncthreads();
  for (int g = 0; g < 4; ++g) {
    size_t qbase = ((size_t)((b*2 + kh)*4 + g)*4096 + qt*64) * 64 + (size_t)(w*16 + row)*64;
    bhalf8 a0 = LD8(&qrh[qbase + kg]);
    bhalf8 a1 = LD8(&qrh[qbase + 32 + kg]);
    f32x4 sc[12];
#pragma unroll
    for (int nf = 0; nf < 12; ++nf) sc[nf] = zero4();
#pragma unroll
    for (int kk = 0; kk < 2; ++kk) {
      bhalf8 a = kk ? a1 : a0;
#pragma unroll
      for (int nf = 0; nf < 12; ++nf) {
        bhalf8 bk = LD8(&sK[(nf*16 + row)*72 + kk*32 + kg]);
        sc[nf] = MFMA(a, bk, sc[nf]);
      }
    }
    float mx[4] = {-1e30f, -1e30f, -1e30f, -1e30f};
#pragma unroll
    for (int nf = 0; nf < 12; ++nf)
#pragma unroll
      for (int i = 0; i < 4; ++i) {
        float v = sc[nf][i] * 0.125f;
        sc[nf][i] = v;
        mx[i] = fmaxf(mx[i], v);
      }
#pragma unroll
    for (int i = 0; i < 4; ++i)
#pragma unroll
      for (int o = 1; o < 16; o <<= 1) mx[i] = fmaxf(mx[i], __shfl_xor(mx[i], o));
    float sum[4] = {0.f, 0.f, 0.f, 0.f};
#pragma unroll
    for (int nf = 0; nf < 12; ++nf)
#pragma unroll
      for (int i = 0; i < 4; ++i) {
        float p = expf(sc[nf][i] - mx[i]);
        sc[nf][i] = p;
        sum[i] += p;
      }
#pragma unroll
    for (int i = 0; i < 4; ++i)
#pragma unroll
      for (int o = 1; o < 16; o <<= 1) sum[i] += __shfl_xor(sum[i], o);
    float inv[4];
#pragma unroll
    for (int i = 0; i < 4; ++i) inv[i] = 1.0f / sum[i];
#pragma unroll
    for (int nf = 0; nf < 12; ++nf)
#pragma unroll
      for (int i = 0; i < 4; ++i)
        sP[(w*16 + (l >> 4)*4 + i)*200 + nf*16 + (l & 15)] = f2bf(sc[nf][i] * inv[i]);
    f32x4 ovv[4];
#pragma unroll
    for (int nf = 0; nf < 4; ++nf) ovv[nf] = zero4();
#pragma unroll
    for (int kk = 0; kk < 6; ++kk) {
      bhalf8 a = LD8(&sP[(w*16 + row)*200 + kk*32 + kg]);
#pragma unroll
      for (int nf = 0; nf < 4; ++nf) {
        bhalf8 bv = LD8(&sVT[(nf*16 + row)*200 + kk*32 + kg]);
        ovv[nf] = MFMA(a, bv, ovv[nf]);
      }
    }
    int hq = kh*4 + g;
#pragma unroll
    for (int i = 0; i < 4; ++i) {
      int q = qt*64 + w*16 + (l >> 4)*4 + i;
      float gate = g32[((size_t)b*4096 + q)*24 + hq*3 + 1];
#pragma unroll
      for (int nf = 0; nf < 4; ++nf) {
        int d = nf*16 + (l & 15);
        size_t oi = (((size_t)b*4096 + q)*8 + hq)*64 + d;
        comb_c[oi] = f2bf(bf2f(comb_c[oi]) + bf2f(comb_s[oi]) + gate * ovv[nf][i]);
      }
    }
  }
}

// ================= launch =================

extern "C" void kernel_launch(void* const* d_in, const int* in_sizes, int n_in,
                              void* d_out, int out_size, void* d_ws, size_t ws_size,
                              hipStream_t stream) {
  const float* x     = (const float*)d_in[0];
  const float* pos   = (const float*)d_in[1];
  const float* pe_w  = (const float*)d_in[2];
  const float* pe_b  = (const float*)d_in[3];
  const float* gamma = (const float*)d_in[4];
  const float* wq    = (const float*)d_in[5];
  const float* wk    = (const float*)d_in[6];
  const float* wv    = (const float*)d_in[7];
  const float* k_pos = (const float*)d_in[8];
  const float* v_pos = (const float*)d_in[9];
  const float* k_w1  = (const float*)d_in[10];
  const float* k_b1  = (const float*)d_in[11];
  const float* k_w2  = (const float*)d_in[12];
  const float* k_b2  = (const float*)d_in[13];
  const float* v_w1  = (const float*)d_in[14];
  const float* v_b1  = (const float*)d_in[15];
  const float* v_w2  = (const float*)d_in[16];
  const float* v_b2  = (const float*)d_in[17];
  const float* mem_k = (const float*)d_in[18];
  const float* mem_v = (const float*)d_in[19];
  const float* w_cmb = (const float*)d_in[20];
  const float* w_out = (const float*)d_in[21];
  float* out = (float*)d_out;
  char* ws = (char*)d_ws;

  // ---- region plan (aliased lifetimes), ~244 MiB ----
  size_t off = 0;
  auto A = [&](size_t b) { size_t o = off; off += (b + 255) & ~(size_t)255; return o; };
  const size_t oR1 = A(100663296);  // [h_hi|h_lo|-] -> [w1kh|w1kl|w1vh] -> [comb_c|comb_s|-]
  const size_t oR2 = A(67108864);   // qrh|qrl (live through fine)
  const size_t oR4 = A(16777216);   // th|tl
  const size_t oR5 = A(16777216);   // v16->tv | vbh
  const size_t oR6 = A(16777216);   // kbh|kbl
  const size_t oR7 = A(16777216);   // krb|vT
  const size_t oR8 = A(3145728);    // g32
  const size_t oR9 = A(2097152);    // wch|wcl
  const size_t o_w2 = A(1572864);   // w2h|w2l|w2vh (written in prep kernel, own region)
  const size_t o_cos = A(524288),  o_sin = A(524288);
  const size_t o_ckh = A(163840),  o_ckl = A(163840);
  const size_t o_cvT = A(196608);
  const size_t o_woh = A(524288);
  const size_t o_imp = A(262144);
  const size_t o_part = A(8388608);   // stage-2 partials: k 4MB + v 4MB

  if (ws_size < off) {  // diagnostic: absmax will read ~ws_size in MiB
    nsa_sentinel<<<(out_size + 255)/256, 256, 0, stream>>>(out, out_size, (float)(ws_size >> 20));
    return;
  }

#define WP(T, o) ((T*)(ws + (o)))
  u16*  h_hi = WP(u16, oR1);           u16* h_lo = WP(u16, oR1 + 33554432);
  u16*  w1kh = WP(u16, oR1);           u16* w1kl = WP(u16, oR1 + 33554432);
  u16*  w1vh = WP(u16, oR1 + 67108864);
  u16*  combc = WP(u16, oR1);          // bf16 comb_c (32MB), after w1kh dead
  u16*  combs = WP(u16, oR1 + 33554432);  // bf16 comb_s (32MB), after w1kl dead
  u16*  qrh  = WP(u16, oR2);           u16* qrl  = WP(u16, oR2 + 33554432);
  u16*  th   = WP(u16, oR4);           u16* tl   = WP(u16, oR4 + 8388608);
  u16*  v16b = WP(u16, oR5);           u16* vbh  = WP(u16, oR5 + 8388608);
  u16*  tv   = WP(u16, oR5);           // alias: v16 dead after vT16
  u16*  kbh  = WP(u16, oR6);           u16* kbl  = WP(u16, oR6 + 8388608);
  u16*  krb  = WP(u16, oR7);           u16* vTb  = WP(u16, oR7 + 8388608);
  float* g32 = WP(float, oR8);
  u16*  wch  = WP(u16, oR9);           u16* wcl  = WP(u16, oR9 + 917504);
  u16*  w2h  = WP(u16, o_w2);          u16* w2l  = WP(u16, o_w2 + 524288);
  u16*  w2vh = WP(u16, o_w2 + 1048576);
  float* cosb = WP(float, o_cos);      float* sinb = WP(float, o_sin);
  u16*  ckh  = WP(u16, o_ckh);         u16* ckl  = WP(u16, o_ckl);
  u16*  cvT  = WP(u16, o_cvT);
  u16*  woh  = WP(u16, o_woh);
  float* imp = WP(float, o_imp);
  float* part = WP(float, o_part);

  nsa_hnorm<<<32768, 256, 0, stream>>>(x, pos, pe_w, pe_b, gamma, h_hi, h_lo);
  // merged prep: wcat + rope tables + w_out^T + w2^T (all input-only)
  nsa_wcat_rope<<<2496, 256, 0, stream>>>(wq, wk, wv, w_cmb, wch, wcl, cosb, sinb,
      w_out, woh, k_w2, w2h, w2l, v_w2, w2vh);
  // projection: single launch; q/k tiles split, v/gate tiles plain (runtime dsp)
  nsa_gemm<true, 0><<<dim3(256, 7, 1), 256, 0, stream>>>(h_hi, h_lo, wch, wcl, 512, 896,
      cosb, sinb, qrh, qrl, g32, k_pos, v_pos, krb, kbh, kbl, v16b, vbh);
  nsa_vT16<<<1024, 256, 0, stream>>>(v16b, vTb);
  // w1 transposes (k split, v plain); overwrite h after projection consumed it
  nsa_wT2<<<dim3(64, 64, 2), 256, 0, stream>>>(k_w1, w1kh, w1kl, v_w1, w1vh, nullptr, 4096, 4096);
  // merged MLP stage-1 (k split + v plain, fused bias+relu epilogue) [R12-best version]
  nsa_mlp1<<<512, 256, 0, stream>>>(kbh, kbl, vbh, w1kh, w1kl, w1vh, k_b1, v_b1, th, tl, tv);
  // merged stage-2 + reduction
  nsa_gemm64m<<<dim3(16, 32), 256, 0, stream>>>(th, tl, tv, w2h, w2l, w2vh, part);
  nsa_red_ckcv<<<704, 256, 0, stream>>>(part, mem_k, k_b2, mem_v, v_b2, ckh, ckl, cvT);
  // merged comp+slide (slide first), then fine (inline top2 + 3-way combine)
  nsa_attn_cs<<<1536, 256, 0, stream>>>(qrh, qrl, ckh, ckl, cvT, krb, vTb, g32, combc, combs, imp);
  nsa_attn_fine<<<1024, 256, 0, stream>>>(qrh, krb, vTb, imp, g32, combc, combs);
  // output projection (plain bf16, A = comb_c directly)
  nsa_gemm<false, 2><<<dim3(256, 4, 1), 256, 0, stream>>>(combc, nullptr, woh, nullptr, 512, 512,
      nullptr, out, nullptr, nullptr, nullptr, nullptr, nullptr, nullptr, nullptr, nullptr,
      nullptr, nullptr);
#undef WP
}